// Round 3
// baseline (1909.228 us; speedup 1.0000x reference)
//
#include <hip/hip_runtime.h>

// Problem constants (fixed by the reference)
#define P 8
#define T 200
#define C 20
#define F 512
#define NQ 1024
#define MAXN 40                    // max samples per class we support (true ~10±4)
#define MMAX (T + MAXN)            // 240
#define PACK ((MMAX*(MMAX+1))/2)   // 28920 packed lower-tri floats (LDS layout in k_factor)
#define PACKA 29280                // row-padded-to-4 packed layout (global W layout) = rowS(MMAX)
#define QL (NQ*C)                  // 20480 logits
#define NB 16                      // Cholesky panel width

// Workspace layout (float offsets)
enum : int {
  OFF_G    = 0,                       // P*T*T      = 320000
  OFF_SQ   = OFF_G   + P*T*T,         // P*T*NQ     = 1638400
  OFF_G1   = OFF_SQ  + P*T*NQ,        // P*T
  OFF_GG   = OFF_G1  + P*T,           // P
  OFF_GM   = OFF_GG  + P,             // P*T*C
  OFF_GMC  = OFF_GM  + P*T*C,         // P*C
  OFF_MM   = OFF_GMC + P*C,           // P*C
  OFF_GQ   = OFF_MM  + P*C,           // P*NQ
  OFF_QN   = OFF_GQ  + P*NQ,          // P*NQ
  OFF_MQ   = OFF_QN  + P*NQ,          // P*C*NQ
  OFF_W    = OFF_MQ  + P*C*NQ,        // P*C*PACKA : packed L (4-aligned rows), diag 16x16 blocks INVERTED
  OFF_QUAD = OFF_W   + P*C*PACKA,     // P*NQ*C
  OFF_CLSF = OFF_QUAD+ P*NQ*C,        // C*8 scalars
  OFF_INT  = OFF_CLSF+ C*8            // int region: counts[C], idx[C*MAXN]
};

__device__ __forceinline__ int offr(int i){ return (i*(i+1))>>1; }

// 4-aligned row-padded packed layout: row i at rowS(i), length padded to mult of 4.
// rowS(i) = sum_{j<i} round4(j+1); closed form with a=i>>2, r=i&3.
__device__ __forceinline__ int rowS(int i){
  int a = i >> 2, r = i & 3;
  return 8*a*(a+1) + 4*r*(a+1);
}

// flat packed index e -> row i (lower triangle, row-packed, offr layout)
__device__ __forceinline__ int row_of(int e){
  int i = (int)((sqrtf(8.f*(float)e + 1.f) - 1.f) * 0.5f);
  while (offr(i+1) <= e) ++i;
  while (offr(i) > e) --i;
  return i;
}

// ---------------- setup: counts, per-class index lists, scalars ----------------
__global__ void k_setup(const int* lab, float* ws){
  int c = threadIdx.x;
  if (c >= C) return;
  int* wsI = (int*)(ws + OFF_INT);
  int n = 0;
  for (int t = 0; t < T; ++t){
    if (lab[t] == c){ if (n < MAXN) wsI[C + c*MAXN + n] = t; ++n; }
  }
  if (n > MAXN) n = MAXN;
  wsI[c] = n;
  float nf    = (float)n;
  float nsafe = fmaxf(nf, 1.0f);
  float dn    = fmaxf(nf - 1.0f, 1.0f);
  float lam   = nsafe / (nsafe + 1.0f);
  float sv    = (1.0f - lam) / (float)(T - 1);
  float av    = lam / dn;
  float* cf = ws + OFF_CLSF + c*8;
  cf[0] = nsafe; cf[1] = dn; cf[2] = lam; cf[3] = sv; cf[4] = av;
  cf[5] = sqrtf(sv); cf[6] = sqrtf(av); cf[7] = 0.0f;
}

// ---------------- G = X X^T per p (200x200) ----------------
__global__ __launch_bounds__(256) void k_gram(const float* X, float* ws){
  __shared__ float Xi[32][33];
  __shared__ float Xj[32][33];
  const int p = blockIdx.z, i0 = blockIdx.y*32, j0 = blockIdx.x*32;
  const int tx = threadIdx.x, ty = threadIdx.y;
  const int tid = ty*16 + tx;
  const float* Xp = X + (size_t)p*T*F;
  float acc[2][2] = {{0.f,0.f},{0.f,0.f}};
  for (int kb = 0; kb < F; kb += 32){
    for (int e = tid; e < 32*32; e += 256){
      int r = e >> 5, kk = e & 31;
      Xi[r][kk] = (i0+r < T) ? Xp[(i0+r)*F + kb+kk] : 0.f;
      Xj[r][kk] = (j0+r < T) ? Xp[(j0+r)*F + kb+kk] : 0.f;
    }
    __syncthreads();
    for (int kk = 0; kk < 32; ++kk){
      float a0 = Xi[2*ty][kk],   a1 = Xi[2*ty+1][kk];
      float b0 = Xj[2*tx][kk],   b1 = Xj[2*tx+1][kk];
      acc[0][0] += a0*b0; acc[0][1] += a0*b1;
      acc[1][0] += a1*b0; acc[1][1] += a1*b1;
    }
    __syncthreads();
  }
  float* Gp = ws + OFF_G + (size_t)p*T*T;
  for (int a = 0; a < 2; ++a)
    for (int b = 0; b < 2; ++b){
      int i = i0 + 2*ty + a, j = j0 + 2*tx + b;
      if (i < T && j < T) Gp[i*T + j] = acc[a][b];
    }
}

// ---------------- per-p stats: g1, gg, Gm, gmc, mm ----------------
__global__ __launch_bounds__(256) void k_pstats(float* ws){
  const int p = blockIdx.x, tid = threadIdx.x;
  const int* wsI = (const int*)(ws + OFF_INT);
  const float* Gp = ws + OFF_G + (size_t)p*T*T;
  float* g1 = ws + OFF_G1 + p*T;
  for (int t = tid; t < T; t += 256){
    float s = 0.f;
    for (int u = 0; u < T; ++u) s += Gp[t*T + u];
    g1[t] = s * (1.0f/T);
  }
  __syncthreads();
  if (tid == 0){
    float s = 0.f;
    for (int t = 0; t < T; ++t) s += g1[t];
    ws[OFF_GG + p] = s * (1.0f/T);
  }
  float* Gm = ws + OFF_GM + (size_t)p*T*C;
  for (int t = tid; t < T; t += 256){
    for (int c = 0; c < C; ++c){
      int n = wsI[c];
      const int* idxc = wsI + C + c*MAXN;
      float s = 0.f;
      for (int j = 0; j < n; ++j) s += Gp[t*T + idxc[j]];
      Gm[t*C + c] = s / ws[OFF_CLSF + c*8];
    }
  }
  __syncthreads();
  if (tid < C){
    int c = tid, n = wsI[c];
    const int* idxc = wsI + C + c*MAXN;
    float s = 0.f;
    for (int t = 0; t < T; ++t) s += Gm[t*C + c];
    ws[OFF_GMC + p*C + c] = s * (1.0f/T);
    float s2 = 0.f;
    for (int j = 0; j < n; ++j) s2 += Gm[idxc[j]*C + c];
    ws[OFF_MM + p*C + c] = s2 / ws[OFF_CLSF + c*8];
  }
}

// ---------------- class means -> output part 2 ----------------
__global__ __launch_bounds__(256) void k_means(const float* X, const float* ws, float* out){
  const int blk = blockIdx.x, p = blk / C, c = blk % C;
  const int* wsI = (const int*)(ws + OFF_INT);
  const int n = wsI[c];
  const int* idxc = wsI + C + c*MAXN;
  const float nf = ws[OFF_CLSF + c*8];
  const float* Xp = X + (size_t)p*T*F;
  float* o = out + QL + (size_t)(p*C + c)*F;
  for (int f = threadIdx.x; f < F; f += 256){
    float s = 0.f;
    for (int j = 0; j < n; ++j) s += Xp[idxc[j]*F + f];
    o[f] = s / nf;
  }
}

// ---------------- SQ = X Q^T per p (200x1024) ----------------
__global__ __launch_bounds__(256) void k_sq(const float* X, const float* Qf, float* ws){
  __shared__ float Xt[32][33];
  __shared__ float Qt[64][33];
  const int p = blockIdx.z, t0 = blockIdx.x*32, q0 = blockIdx.y*64;
  const int tx = threadIdx.x, ty = threadIdx.y;
  const int tid = ty*16 + tx;
  const float* Xp = X  + (size_t)p*T*F;
  const float* Qp = Qf + (size_t)p*NQ*F;
  float acc[2][4] = {};
  for (int kb = 0; kb < F; kb += 32){
    for (int e = tid; e < 32*32; e += 256){
      int r = e >> 5, kk = e & 31;
      Xt[r][kk] = (t0+r < T) ? Xp[(t0+r)*F + kb+kk] : 0.f;
    }
    for (int e = tid; e < 64*32; e += 256){
      int r = e >> 5, kk = e & 31;
      Qt[r][kk] = Qp[(q0+r)*F + kb+kk];
    }
    __syncthreads();
    for (int kk = 0; kk < 32; ++kk){
      float a0 = Xt[2*ty][kk], a1 = Xt[2*ty+1][kk];
      float b0 = Qt[4*tx][kk], b1 = Qt[4*tx+1][kk], b2 = Qt[4*tx+2][kk], b3 = Qt[4*tx+3][kk];
      acc[0][0] += a0*b0; acc[0][1] += a0*b1; acc[0][2] += a0*b2; acc[0][3] += a0*b3;
      acc[1][0] += a1*b0; acc[1][1] += a1*b1; acc[1][2] += a1*b2; acc[1][3] += a1*b3;
    }
    __syncthreads();
  }
  float* SQp = ws + OFF_SQ + (size_t)p*T*NQ;
  for (int a = 0; a < 2; ++a){
    int t = t0 + 2*ty + a;
    if (t < T)
      for (int b = 0; b < 4; ++b)
        SQp[t*NQ + q0 + 4*tx + b] = acc[a][b];
  }
}

// ---------------- per-q stats: gq, mq (qn moved to k_qnorm) ----------------
__global__ __launch_bounds__(256) void k_qstats(float* ws){
  const int p = blockIdx.y;
  const int q = blockIdx.x*256 + threadIdx.x;
  const int* wsI = (const int*)(ws + OFF_INT);
  const float* SQp = ws + OFF_SQ + (size_t)p*T*NQ;
  float s = 0.f;
  for (int t = 0; t < T; ++t) s += SQp[t*NQ + q];
  ws[OFF_GQ + p*NQ + q] = s * (1.0f/T);
  for (int c = 0; c < C; ++c){
    int n = wsI[c];
    const int* idxc = wsI + C + c*MAXN;
    float sc = 0.f;
    for (int j = 0; j < n; ++j) sc += SQp[idxc[j]*NQ + q];
    ws[OFF_MQ + ((size_t)(p*C + c))*NQ + q] = sc / ws[OFF_CLSF + c*8];
  }
}

// ---------------- qn = ||q||^2, one wave per row, float4 + shuffle reduce ----------------
__global__ __launch_bounds__(256) void k_qnorm(const float* Qf, float* ws){
  const int row  = blockIdx.x*4 + (threadIdx.x >> 6);   // row = p*NQ + q
  const int lane = threadIdx.x & 63;
  const float4* q4p = (const float4*)(Qf + (size_t)row*F);
  float4 v0 = q4p[lane];
  float4 v1 = q4p[lane + 64];
  float s = v0.x*v0.x + v0.y*v0.y + v0.z*v0.z + v0.w*v0.w
          + v1.x*v1.x + v1.y*v1.y + v1.z*v1.z + v1.w*v1.w;
  for (int off = 32; off; off >>= 1) s += __shfl_down(s, off, 64);
  if (lane == 0) ws[OFF_QN + row] = s;
}

// ---------------- build M, BLOCKED packed-LDS Cholesky; invert 16x16 diag blocks
//                  in place; store in 4-aligned row-padded packed layout ----------------
__global__ __launch_bounds__(256) void k_factor(float* ws){
  __shared__ float Lp[PACK];            // packed lower triangle, 115.7 KB
  __shared__ float Pn[MMAX+4][NB+1];    // padded panel buffer, 16.6 KB
  const int blk = blockIdx.x, p = blk / C, c = blk % C;
  const int tid = threadIdx.x;
  const int* wsI = (const int*)(ws + OFF_INT);
  const int n = wsI[c];
  const int m = T + n;
  const int* idxc = wsI + C + c*MAXN;
  const float* cf = ws + OFF_CLSF + c*8;
  const float sv = cf[3], av = cf[4], sqsa = cf[5]*cf[6];
  const float* Gp  = ws + OFF_G  + (size_t)p*T*T;
  const float* g1p = ws + OFF_G1 + p*T;
  const float  ggv = ws[OFF_GG + p];
  const float* Gmp = ws + OFF_GM + (size_t)p*T*C;
  const float gmcv = ws[OFF_GMC + p*C + c];
  const float mmv  = ws[OFF_MM  + p*C + c];
  const int tot = (m*(m+1)) >> 1;

  // ---- build M packed, fully parallel over the flat triangle ----
  for (int e = tid; e < tot; e += 256){
    int i = row_of(e);
    int j = e - offr(i);
    float v;
    if (i < T){
      v = sv*(Gp[i*T + j] - g1p[i] - g1p[j] + ggv);
      if (j == i) v += 1.0f;
    } else {
      int ua = idxc[i - T];
      if (j < T){
        v = sqsa*(Gp[ua*T + j] - Gmp[j*C + c] - g1p[ua] + gmcv);
      } else {
        int ub = idxc[j - T];
        v = av*(Gp[ua*T + ub] - Gmp[ua*C + c] - Gmp[ub*C + c] + mmv);
        if (j == i) v += 1.0f;
      }
    }
    Lp[e] = v;
  }
  __syncthreads();

  // ---- blocked right-looking Cholesky ----
  for (int k0 = 0; k0 < m; k0 += NB){
    const int kb = min(NB, m - k0);
    const int rows = m - k0;
    const int rowsP = (rows + 3) & ~3;   // zero-fill so 4x4 tiles read clean data
    for (int e = tid; e < rowsP*NB; e += 256){
      int r = e >> 4, cl = e & 15;
      float v = 0.f;
      if (r < rows && cl < kb && (r >= NB || cl <= r)) v = Lp[offr(k0+r) + k0 + cl];
      Pn[r][cl] = v;
    }
    __syncthreads();
    // mini-Cholesky on the panel (conflict-free buffer; pivots >= 1, no pivoting)
    for (int jl = 0; jl < kb; ++jl){
      float d = Pn[jl][jl];
      float inv = 1.0f / sqrtf(d);
      __syncthreads();
      for (int i = jl + tid; i < rows; i += 256) Pn[i][jl] *= inv;
      __syncthreads();
      for (int i = jl + 1 + tid; i < rows; i += 256){
        float pij = Pn[i][jl];
        for (int cl = jl + 1; cl < kb; ++cl) Pn[i][cl] -= pij * Pn[cl][jl];
      }
      __syncthreads();
    }
    // invert the kb x kb lower-tri diagonal block; write INVERSE into Lp diag slots
    if (tid < kb){
      int j = tid;
      float x[NB];
      x[j] = 1.0f / Pn[j][j];
      for (int i = j + 1; i < kb; ++i){
        float s = 0.f;
        for (int k = j; k < i; ++k) s += Pn[i][k] * x[k];
        x[i] = -s / Pn[i][i];
      }
      for (int i = j; i < kb; ++i) Lp[offr(k0+i) + k0 + j] = x[i];
    }
    // write back off-diagonal panel rows (final L values)
    for (int e = tid; e < (rows - kb)*NB; e += 256){
      int r = kb + (e >> 4), cl = e & 15;
      if (cl < kb) Lp[offr(k0+r) + k0 + cl] = Pn[r][cl];
    }
    // trailing SYRK update, 4x4 register tiles
    const int rs = rows - kb;
    if (rs > 0){
      const int nt4 = (rs + 3) >> 2;
      const int ntile = (nt4*(nt4+1)) >> 1;
      for (int e = tid; e < ntile; e += 256){
        int ti = row_of(e);
        int tj = e - offr(ti);
        int i0 = kb + 4*ti, j0 = kb + 4*tj;
        float acc[4][4] = {};
        #pragma unroll 4
        for (int k = 0; k < NB; ++k){
          float a0 = Pn[i0][k], a1 = Pn[i0+1][k], a2 = Pn[i0+2][k], a3 = Pn[i0+3][k];
          float b0 = Pn[j0][k], b1 = Pn[j0+1][k], b2 = Pn[j0+2][k], b3 = Pn[j0+3][k];
          acc[0][0] += a0*b0; acc[0][1] += a0*b1; acc[0][2] += a0*b2; acc[0][3] += a0*b3;
          acc[1][0] += a1*b0; acc[1][1] += a1*b1; acc[1][2] += a1*b2; acc[1][3] += a1*b3;
          acc[2][0] += a2*b0; acc[2][1] += a2*b1; acc[2][2] += a2*b2; acc[2][3] += a2*b3;
          acc[3][0] += a3*b0; acc[3][1] += a3*b1; acc[3][2] += a3*b2; acc[3][3] += a3*b3;
        }
        #pragma unroll
        for (int u = 0; u < 4; ++u){
          int gi = k0 + i0 + u;
          if (gi < m){
            int og = offr(gi);
            #pragma unroll
            for (int v2 = 0; v2 < 4; ++v2){
              int gj = k0 + j0 + v2;
              if (gj <= gi) Lp[og + gj] -= acc[u][v2];
            }
          }
        }
      }
    }
    __syncthreads();
  }

  // ---- store packed L (inverted diag blocks) into 4-aligned row-padded layout ----
  float* Wg = ws + OFF_W + (size_t)blk * PACKA;
  for (int e = tid; e < tot; e += 256){
    int i = row_of(e);
    int j = e - offr(i);
    Wg[rowS(i) + j] = Lp[e];
  }
}

// ---------------- apply: blocked TRSM (32-row phases, 4 rows x 2 queries per lane),
//                  quad = ||d||^2 - ||L^-1 e||^2 ----------------
__global__ __launch_bounds__(256) void k_apply(float* ws){
  __shared__ float E[MMAX][64];   // e, progressively overwritten with z; 61.4 KB
  __shared__ float R[16][64];     // publish buffer; 4 KB
  const int p = blockIdx.z, c = blockIdx.y, q0 = blockIdx.x*64;
  const int tid = threadIdx.x;
  const int* wsI = (const int*)(ws + OFF_INT);
  const int n = wsI[c], m = T + n;
  const int* idxc = wsI + C + c*MAXN;
  const float* cf = ws + OFF_CLSF + c*8;
  const float sqs = cf[5], sqa = cf[6];
  const float gmcv = ws[OFF_GMC + p*C + c];
  const float mmv  = ws[OFF_MM  + p*C + c];
  const float* Gmp = ws + OFF_GM + (size_t)p*T*C;
  const float* SQp = ws + OFF_SQ + (size_t)p*T*NQ;
  const float* gqp = ws + OFF_GQ + p*NQ + q0;
  const float* qnp = ws + OFF_QN + p*NQ + q0;
  const float* mqp = ws + OFF_MQ + ((size_t)(p*C + c))*NQ + q0;
  const float* Wb  = ws + OFF_W + (size_t)(p*C + c)*PACKA;

  for (int lin = tid; lin < m*64; lin += 256){
    int j = lin >> 6, ql = lin & 63;
    float v;
    if (j < T){
      v = sqs*(Gmp[j*C + c] - SQp[j*NQ + q0 + ql] - gmcv + gqp[ql]);
    } else {
      int u = idxc[j - T];
      v = sqa*(Gmp[u*C + c] - SQp[u*NQ + q0 + ql] - mmv + mqp[ql]);
    }
    E[j][ql] = v;
  }
  __syncthreads();

  const int rg = tid >> 5;          // 0..7
  const int qg = tid & 31;          // 0..31
  const int q2 = qg*2;              // 2 consecutive queries
  float ss0 = 0.f, ss1 = 0.f;
  const int nph = (m + 31) >> 5;

  for (int b = 0; b < nph; ++b){
    const int k0 = b*32;
    int   r[4];  bool act[4];  const float* wr[4];
    float a[4][2];
    #pragma unroll
    for (int s = 0; s < 4; ++s){
      r[s]   = k0 + rg + 8*s;
      act[s] = (r[s] < m);
      wr[s]  = Wb + (act[s] ? rowS(r[s]) : 0);
      a[s][0] = 0.f; a[s][1] = 0.f;
    }
    // ---- stage 1: a[s] = sum_{k<k0} W[r_s][k] * z[k]  (float4 W, shared E reads) ----
    for (int k = 0; k < k0; k += 4){
      float2 e0 = *(const float2*)&E[k  ][q2];
      float2 e1 = *(const float2*)&E[k+1][q2];
      float2 e2 = *(const float2*)&E[k+2][q2];
      float2 e3 = *(const float2*)&E[k+3][q2];
      #pragma unroll
      for (int s = 0; s < 4; ++s){
        if (act[s]){
          float4 w = *(const float4*)(wr[s] + k);
          a[s][0] += w.x*e0.x + w.y*e1.x + w.z*e2.x + w.w*e3.x;
          a[s][1] += w.x*e0.y + w.y*e1.y + w.z*e2.y + w.w*e3.y;
        }
      }
    }
    // publish upper-half residuals (rows k0 .. k0+15)
    #pragma unroll
    for (int s = 0; s < 2; ++s){
      if (act[s]){
        float2 ev = *(const float2*)&E[r[s]][q2];
        R[rg + 8*s][q2]   = ev.x - a[s][0];
        R[rg + 8*s][q2+1] = ev.y - a[s][1];
      }
    }
    __syncthreads();
    // ---- upper diag solve: z_i = sum_{j<=i} Dinv[i][j] * R[j] ----
    #pragma unroll
    for (int t2 = 0; t2 < 2; ++t2){
      int i = rg + 8*t2, gr = k0 + i;
      if (gr < m){
        const float* dr = Wb + rowS(gr) + k0;
        float z0 = 0.f, z1 = 0.f;
        for (int j = 0; j <= i; ++j){
          float dv = dr[j];
          float2 rv = *(const float2*)&R[j][q2];
          z0 += dv*rv.x; z1 += dv*rv.y;
        }
        ss0 += z0*z0; ss1 += z1*z1;
        E[gr][q2] = z0; E[gr][q2+1] = z1;
      }
    }
    __syncthreads();
    // ---- middle: lower-half rows vs the 16 freshly-solved upper rows ----
    #pragma unroll
    for (int s = 2; s < 4; ++s){
      if (act[s]){
        for (int jj = 0; jj < 16; jj += 4){
          float4 w = *(const float4*)(wr[s] + k0 + jj);
          float2 e0 = *(const float2*)&E[k0+jj  ][q2];
          float2 e1 = *(const float2*)&E[k0+jj+1][q2];
          float2 e2 = *(const float2*)&E[k0+jj+2][q2];
          float2 e3 = *(const float2*)&E[k0+jj+3][q2];
          a[s][0] += w.x*e0.x + w.y*e1.x + w.z*e2.x + w.w*e3.x;
          a[s][1] += w.x*e0.y + w.y*e1.y + w.z*e2.y + w.w*e3.y;
        }
        float2 ev = *(const float2*)&E[r[s]][q2];
        R[rg + 8*(s-2)][q2]   = ev.x - a[s][0];
        R[rg + 8*(s-2)][q2+1] = ev.y - a[s][1];
      }
    }
    __syncthreads();
    // ---- lower diag solve ----
    #pragma unroll
    for (int t2 = 0; t2 < 2; ++t2){
      int i = rg + 8*t2, gr = k0 + 16 + i;
      if (gr < m){
        const float* dr = Wb + rowS(gr) + k0 + 16;
        float z0 = 0.f, z1 = 0.f;
        for (int j = 0; j <= i; ++j){
          float dv = dr[j];
          float2 rv = *(const float2*)&R[j][q2];
          z0 += dv*rv.x; z1 += dv*rv.y;
        }
        ss0 += z0*z0; ss1 += z1*z1;
        E[gr][q2] = z0; E[gr][q2+1] = z1;
      }
    }
    __syncthreads();
  }

  // ---- reduce ||z||^2 over the 8 row-groups per query ----
  R[rg][q2]   = ss0;
  R[rg][q2+1] = ss1;
  __syncthreads();
  if (tid < 64){
    int q = tid;
    float tt = 0.f;
    #pragma unroll
    for (int j = 0; j < 8; ++j) tt += R[j][q];
    float quad = mmv - 2.f*mqp[q] + qnp[q] - tt;
    ws[OFF_QUAD + ((size_t)p*NQ + q0 + q)*C + c] = quad;
  }
}

// ---------------- logits: mean over p ----------------
__global__ void k_logits(const float* ws, float* out){
  int lin = blockIdx.x*256 + threadIdx.x;
  if (lin < QL){
    float s = 0.f;
    for (int p = 0; p < P; ++p) s += ws[OFF_QUAD + (size_t)p*NQ*C + lin];
    out[lin] = -s * (1.0f/P);
  }
}

extern "C" void kernel_launch(void* const* d_in, const int* in_sizes, int n_in,
                              void* d_out, int out_size, void* d_ws, size_t ws_size,
                              hipStream_t stream){
  const float* X   = (const float*)d_in[0];
  const int*   lab = (const int*)d_in[1];
  const float* Qf  = (const float*)d_in[2];
  float* out = (float*)d_out;
  float* ws  = (float*)d_ws;

  k_setup <<<1, 64, 0, stream>>>(lab, ws);
  k_gram  <<<dim3(7,7,P),  dim3(16,16), 0, stream>>>(X, ws);
  k_pstats<<<P, 256, 0, stream>>>(ws);
  k_means <<<P*C, 256, 0, stream>>>(X, ws, out);
  k_sq    <<<dim3(7,16,P), dim3(16,16), 0, stream>>>(X, Qf, ws);
  k_qstats<<<dim3(4,P), 256, 0, stream>>>(ws);
  k_qnorm <<<(P*NQ)/4, 256, 0, stream>>>(Qf, ws);
  k_factor<<<P*C, 256, 0, stream>>>(ws);
  k_apply <<<dim3(16,C,P), 256, 0, stream>>>(ws);
  k_logits<<<QL/256, 256, 0, stream>>>(ws, out);
}

// Round 4
// 1732.726 us; speedup vs baseline: 1.1019x; 1.1019x over previous
//
#include <hip/hip_runtime.h>

// Problem constants (fixed by the reference)
#define P 8
#define T 200
#define C 20
#define F 512
#define NQ 1024
#define MAXN 40                    // max samples per class we support (true ~10±4)
#define MMAX (T + MAXN)            // 240
#define PACK ((MMAX*(MMAX+1))/2)   // 28920 packed lower-tri floats (LDS layout in k_factor)
#define PACKA 29280                // row-padded-to-4 packed layout (global W layout) = rowS(MMAX)
#define QL (NQ*C)                  // 20480 logits
#define NB 16                      // Cholesky panel width

// Workspace layout (float offsets)
enum : int {
  OFF_G    = 0,                       // P*T*T      = 320000
  OFF_SQ   = OFF_G   + P*T*T,         // P*T*NQ     = 1638400
  OFF_G1   = OFF_SQ  + P*T*NQ,        // P*T
  OFF_GG   = OFF_G1  + P*T,           // P
  OFF_GM   = OFF_GG  + P,             // P*T*C
  OFF_GMC  = OFF_GM  + P*T*C,         // P*C
  OFF_MM   = OFF_GMC + P*C,           // P*C
  OFF_GQ   = OFF_MM  + P*C,           // P*NQ
  OFF_QN   = OFF_GQ  + P*NQ,          // P*NQ
  OFF_MQ   = OFF_QN  + P*NQ,          // P*C*NQ
  OFF_W    = OFF_MQ  + P*C*NQ,        // P*C*PACKA : packed L (4-aligned rows), diag blocks INVERTED, rows>=m zeroed
  OFF_QUAD = OFF_W   + P*C*PACKA,     // P*NQ*C
  OFF_CLSF = OFF_QUAD+ P*NQ*C,        // C*8 scalars
  OFF_INT  = OFF_CLSF+ C*8            // int region: counts[C], idx[C*MAXN]
};

__device__ __forceinline__ int offr(int i){ return (i*(i+1))>>1; }

// 4-aligned row-padded packed layout: row i at rowS(i), length padded to mult of 4.
__device__ __forceinline__ int rowS(int i){
  int a = i >> 2, r = i & 3;
  return 8*a*(a+1) + 4*r*(a+1);
}

// flat packed index e -> row i (lower triangle, row-packed, offr layout)
__device__ __forceinline__ int row_of(int e){
  int i = (int)((sqrtf(8.f*(float)e + 1.f) - 1.f) * 0.5f);
  while (offr(i+1) <= e) ++i;
  while (offr(i) > e) --i;
  return i;
}

// ---------------- setup: counts, per-class index lists, scalars ----------------
__global__ void k_setup(const int* lab, float* ws){
  int c = threadIdx.x;
  if (c >= C) return;
  int* wsI = (int*)(ws + OFF_INT);
  int n = 0;
  for (int t = 0; t < T; ++t){
    if (lab[t] == c){ if (n < MAXN) wsI[C + c*MAXN + n] = t; ++n; }
  }
  if (n > MAXN) n = MAXN;
  wsI[c] = n;
  float nf    = (float)n;
  float nsafe = fmaxf(nf, 1.0f);
  float dn    = fmaxf(nf - 1.0f, 1.0f);
  float lam   = nsafe / (nsafe + 1.0f);
  float sv    = (1.0f - lam) / (float)(T - 1);
  float av    = lam / dn;
  float* cf = ws + OFF_CLSF + c*8;
  cf[0] = nsafe; cf[1] = dn; cf[2] = lam; cf[3] = sv; cf[4] = av;
  cf[5] = sqrtf(sv); cf[6] = sqrtf(av); cf[7] = 0.0f;
}

// ---------------- G = X X^T per p (200x200) ----------------
__global__ __launch_bounds__(256) void k_gram(const float* X, float* ws){
  __shared__ float Xi[32][33];
  __shared__ float Xj[32][33];
  const int p = blockIdx.z, i0 = blockIdx.y*32, j0 = blockIdx.x*32;
  const int tx = threadIdx.x, ty = threadIdx.y;
  const int tid = ty*16 + tx;
  const float* Xp = X + (size_t)p*T*F;
  float acc[2][2] = {{0.f,0.f},{0.f,0.f}};
  for (int kb = 0; kb < F; kb += 32){
    for (int e = tid; e < 32*32; e += 256){
      int r = e >> 5, kk = e & 31;
      Xi[r][kk] = (i0+r < T) ? Xp[(i0+r)*F + kb+kk] : 0.f;
      Xj[r][kk] = (j0+r < T) ? Xp[(j0+r)*F + kb+kk] : 0.f;
    }
    __syncthreads();
    for (int kk = 0; kk < 32; ++kk){
      float a0 = Xi[2*ty][kk],   a1 = Xi[2*ty+1][kk];
      float b0 = Xj[2*tx][kk],   b1 = Xj[2*tx+1][kk];
      acc[0][0] += a0*b0; acc[0][1] += a0*b1;
      acc[1][0] += a1*b0; acc[1][1] += a1*b1;
    }
    __syncthreads();
  }
  float* Gp = ws + OFF_G + (size_t)p*T*T;
  for (int a = 0; a < 2; ++a)
    for (int b = 0; b < 2; ++b){
      int i = i0 + 2*ty + a, j = j0 + 2*tx + b;
      if (i < T && j < T) Gp[i*T + j] = acc[a][b];
    }
}

// ---------------- per-p stats: g1, gg, Gm, gmc, mm ----------------
__global__ __launch_bounds__(256) void k_pstats(float* ws){
  const int p = blockIdx.x, tid = threadIdx.x;
  const int* wsI = (const int*)(ws + OFF_INT);
  const float* Gp = ws + OFF_G + (size_t)p*T*T;
  float* g1 = ws + OFF_G1 + p*T;
  for (int t = tid; t < T; t += 256){
    float s = 0.f;
    for (int u = 0; u < T; ++u) s += Gp[t*T + u];
    g1[t] = s * (1.0f/T);
  }
  __syncthreads();
  if (tid == 0){
    float s = 0.f;
    for (int t = 0; t < T; ++t) s += g1[t];
    ws[OFF_GG + p] = s * (1.0f/T);
  }
  float* Gm = ws + OFF_GM + (size_t)p*T*C;
  for (int t = tid; t < T; t += 256){
    for (int c = 0; c < C; ++c){
      int n = wsI[c];
      const int* idxc = wsI + C + c*MAXN;
      float s = 0.f;
      for (int j = 0; j < n; ++j) s += Gp[t*T + idxc[j]];
      Gm[t*C + c] = s / ws[OFF_CLSF + c*8];
    }
  }
  __syncthreads();
  if (tid < C){
    int c = tid, n = wsI[c];
    const int* idxc = wsI + C + c*MAXN;
    float s = 0.f;
    for (int t = 0; t < T; ++t) s += Gm[t*C + c];
    ws[OFF_GMC + p*C + c] = s * (1.0f/T);
    float s2 = 0.f;
    for (int j = 0; j < n; ++j) s2 += Gm[idxc[j]*C + c];
    ws[OFF_MM + p*C + c] = s2 / ws[OFF_CLSF + c*8];
  }
}

// ---------------- class means -> output part 2 ----------------
__global__ __launch_bounds__(256) void k_means(const float* X, const float* ws, float* out){
  const int blk = blockIdx.x, p = blk / C, c = blk % C;
  const int* wsI = (const int*)(ws + OFF_INT);
  const int n = wsI[c];
  const int* idxc = wsI + C + c*MAXN;
  const float nf = ws[OFF_CLSF + c*8];
  const float* Xp = X + (size_t)p*T*F;
  float* o = out + QL + (size_t)(p*C + c)*F;
  for (int f = threadIdx.x; f < F; f += 256){
    float s = 0.f;
    for (int j = 0; j < n; ++j) s += Xp[idxc[j]*F + f];
    o[f] = s / nf;
  }
}

// ---------------- SQ = X Q^T per p (200x1024) ----------------
__global__ __launch_bounds__(256) void k_sq(const float* X, const float* Qf, float* ws){
  __shared__ float Xt[32][33];
  __shared__ float Qt[64][33];
  const int p = blockIdx.z, t0 = blockIdx.x*32, q0 = blockIdx.y*64;
  const int tx = threadIdx.x, ty = threadIdx.y;
  const int tid = ty*16 + tx;
  const float* Xp = X  + (size_t)p*T*F;
  const float* Qp = Qf + (size_t)p*NQ*F;
  float acc[2][4] = {};
  for (int kb = 0; kb < F; kb += 32){
    for (int e = tid; e < 32*32; e += 256){
      int r = e >> 5, kk = e & 31;
      Xt[r][kk] = (t0+r < T) ? Xp[(t0+r)*F + kb+kk] : 0.f;
    }
    for (int e = tid; e < 64*32; e += 256){
      int r = e >> 5, kk = e & 31;
      Qt[r][kk] = Qp[(q0+r)*F + kb+kk];
    }
    __syncthreads();
    for (int kk = 0; kk < 32; ++kk){
      float a0 = Xt[2*ty][kk], a1 = Xt[2*ty+1][kk];
      float b0 = Qt[4*tx][kk], b1 = Qt[4*tx+1][kk], b2 = Qt[4*tx+2][kk], b3 = Qt[4*tx+3][kk];
      acc[0][0] += a0*b0; acc[0][1] += a0*b1; acc[0][2] += a0*b2; acc[0][3] += a0*b3;
      acc[1][0] += a1*b0; acc[1][1] += a1*b1; acc[1][2] += a1*b2; acc[1][3] += a1*b3;
    }
    __syncthreads();
  }
  float* SQp = ws + OFF_SQ + (size_t)p*T*NQ;
  for (int a = 0; a < 2; ++a){
    int t = t0 + 2*ty + a;
    if (t < T)
      for (int b = 0; b < 4; ++b)
        SQp[t*NQ + q0 + 4*tx + b] = acc[a][b];
  }
}

// ---------------- per-q stats: gq, mq ----------------
__global__ __launch_bounds__(256) void k_qstats(float* ws){
  const int p = blockIdx.y;
  const int q = blockIdx.x*256 + threadIdx.x;
  const int* wsI = (const int*)(ws + OFF_INT);
  const float* SQp = ws + OFF_SQ + (size_t)p*T*NQ;
  float s = 0.f;
  for (int t = 0; t < T; ++t) s += SQp[t*NQ + q];
  ws[OFF_GQ + p*NQ + q] = s * (1.0f/T);
  for (int c = 0; c < C; ++c){
    int n = wsI[c];
    const int* idxc = wsI + C + c*MAXN;
    float sc = 0.f;
    for (int j = 0; j < n; ++j) sc += SQp[idxc[j]*NQ + q];
    ws[OFF_MQ + ((size_t)(p*C + c))*NQ + q] = sc / ws[OFF_CLSF + c*8];
  }
}

// ---------------- qn = ||q||^2, one wave per row, float4 + shuffle reduce ----------------
__global__ __launch_bounds__(256) void k_qnorm(const float* Qf, float* ws){
  const int row  = blockIdx.x*4 + (threadIdx.x >> 6);   // row = p*NQ + q
  const int lane = threadIdx.x & 63;
  const float4* q4p = (const float4*)(Qf + (size_t)row*F);
  float4 v0 = q4p[lane];
  float4 v1 = q4p[lane + 64];
  float s = v0.x*v0.x + v0.y*v0.y + v0.z*v0.z + v0.w*v0.w
          + v1.x*v1.x + v1.y*v1.y + v1.z*v1.z + v1.w*v1.w;
  for (int off = 32; off; off >>= 1) s += __shfl_down(s, off, 64);
  if (lane == 0) ws[OFF_QN + row] = s;
}

// ---------------- build M, BLOCKED packed-LDS Cholesky; invert 16x16 diag blocks
//                  in place; store in 4-aligned row-padded packed layout; zero rows>=m ----------------
__global__ __launch_bounds__(256) void k_factor(float* ws){
  __shared__ float Lp[PACK];            // packed lower triangle, 115.7 KB
  __shared__ float Pn[MMAX+4][NB+1];    // padded panel buffer, 16.6 KB
  const int blk = blockIdx.x, p = blk / C, c = blk % C;
  const int tid = threadIdx.x;
  const int* wsI = (const int*)(ws + OFF_INT);
  const int n = wsI[c];
  const int m = T + n;
  const int* idxc = wsI + C + c*MAXN;
  const float* cf = ws + OFF_CLSF + c*8;
  const float sv = cf[3], av = cf[4], sqsa = cf[5]*cf[6];
  const float* Gp  = ws + OFF_G  + (size_t)p*T*T;
  const float* g1p = ws + OFF_G1 + p*T;
  const float  ggv = ws[OFF_GG + p];
  const float* Gmp = ws + OFF_GM + (size_t)p*T*C;
  const float gmcv = ws[OFF_GMC + p*C + c];
  const float mmv  = ws[OFF_MM  + p*C + c];
  const int tot = (m*(m+1)) >> 1;

  // ---- build M packed, fully parallel over the flat triangle ----
  for (int e = tid; e < tot; e += 256){
    int i = row_of(e);
    int j = e - offr(i);
    float v;
    if (i < T){
      v = sv*(Gp[i*T + j] - g1p[i] - g1p[j] + ggv);
      if (j == i) v += 1.0f;
    } else {
      int ua = idxc[i - T];
      if (j < T){
        v = sqsa*(Gp[ua*T + j] - Gmp[j*C + c] - g1p[ua] + gmcv);
      } else {
        int ub = idxc[j - T];
        v = av*(Gp[ua*T + ub] - Gmp[ua*C + c] - Gmp[ub*C + c] + mmv);
        if (j == i) v += 1.0f;
      }
    }
    Lp[e] = v;
  }
  __syncthreads();

  // ---- blocked right-looking Cholesky ----
  for (int k0 = 0; k0 < m; k0 += NB){
    const int kb = min(NB, m - k0);
    const int rows = m - k0;
    const int rowsP = (rows + 3) & ~3;   // zero-fill so 4x4 tiles read clean data
    for (int e = tid; e < rowsP*NB; e += 256){
      int r = e >> 4, cl = e & 15;
      float v = 0.f;
      if (r < rows && cl < kb && (r >= NB || cl <= r)) v = Lp[offr(k0+r) + k0 + cl];
      Pn[r][cl] = v;
    }
    __syncthreads();
    // mini-Cholesky on the panel (conflict-free buffer; pivots >= 1, no pivoting)
    for (int jl = 0; jl < kb; ++jl){
      float d = Pn[jl][jl];
      float inv = 1.0f / sqrtf(d);
      __syncthreads();
      for (int i = jl + tid; i < rows; i += 256) Pn[i][jl] *= inv;
      __syncthreads();
      for (int i = jl + 1 + tid; i < rows; i += 256){
        float pij = Pn[i][jl];
        for (int cl = jl + 1; cl < kb; ++cl) Pn[i][cl] -= pij * Pn[cl][jl];
      }
      __syncthreads();
    }
    // invert the kb x kb lower-tri diagonal block; write INVERSE into Lp diag slots
    if (tid < kb){
      int j = tid;
      float x[NB];
      x[j] = 1.0f / Pn[j][j];
      for (int i = j + 1; i < kb; ++i){
        float s = 0.f;
        for (int k = j; k < i; ++k) s += Pn[i][k] * x[k];
        x[i] = -s / Pn[i][i];
      }
      for (int i = j; i < kb; ++i) Lp[offr(k0+i) + k0 + j] = x[i];
    }
    // write back off-diagonal panel rows (final L values)
    for (int e = tid; e < (rows - kb)*NB; e += 256){
      int r = kb + (e >> 4), cl = e & 15;
      if (cl < kb) Lp[offr(k0+r) + k0 + cl] = Pn[r][cl];
    }
    // trailing SYRK update, 4x4 register tiles
    const int rs = rows - kb;
    if (rs > 0){
      const int nt4 = (rs + 3) >> 2;
      const int ntile = (nt4*(nt4+1)) >> 1;
      for (int e = tid; e < ntile; e += 256){
        int ti = row_of(e);
        int tj = e - offr(ti);
        int i0 = kb + 4*ti, j0 = kb + 4*tj;
        float acc[4][4] = {};
        #pragma unroll 4
        for (int k = 0; k < NB; ++k){
          float a0 = Pn[i0][k], a1 = Pn[i0+1][k], a2 = Pn[i0+2][k], a3 = Pn[i0+3][k];
          float b0 = Pn[j0][k], b1 = Pn[j0+1][k], b2 = Pn[j0+2][k], b3 = Pn[j0+3][k];
          acc[0][0] += a0*b0; acc[0][1] += a0*b1; acc[0][2] += a0*b2; acc[0][3] += a0*b3;
          acc[1][0] += a1*b0; acc[1][1] += a1*b1; acc[1][2] += a1*b2; acc[1][3] += a1*b3;
          acc[2][0] += a2*b0; acc[2][1] += a2*b1; acc[2][2] += a2*b2; acc[2][3] += a2*b3;
          acc[3][0] += a3*b0; acc[3][1] += a3*b1; acc[3][2] += a3*b2; acc[3][3] += a3*b3;
        }
        #pragma unroll
        for (int u = 0; u < 4; ++u){
          int gi = k0 + i0 + u;
          if (gi < m){
            int og = offr(gi);
            #pragma unroll
            for (int v2 = 0; v2 < 4; ++v2){
              int gj = k0 + j0 + v2;
              if (gj <= gi) Lp[og + gj] -= acc[u][v2];
            }
          }
        }
      }
    }
    __syncthreads();
  }

  // ---- store packed L (inverted diag blocks) into 4-aligned row-padded layout;
  //      zero the tail region (rows m..MMAX-1) so k_apply can run uniform loops ----
  float* Wg = ws + OFF_W + (size_t)blk * PACKA;
  for (int e = tid; e < tot; e += 256){
    int i = row_of(e);
    int j = e - offr(i);
    Wg[rowS(i) + j] = Lp[e];
  }
  const int z0 = rowS(m);
  for (int e = z0 + tid; e < PACKA; e += 256) Wg[e] = 0.f;
}

// ---------------- apply: blocked TRSM (16-row phases, 2 rows x 2 queries per lane,
//                  uniform loops via zero padding), quad = ||d||^2 - ||L^-1 e||^2 ----------------
__global__ __launch_bounds__(256) void k_apply(float* ws){
  __shared__ float E[MMAX][64];   // e, progressively overwritten with z; 61.4 KB
  __shared__ float R[NB][64];     // residual publish buffer; 4 KB
  const int p = blockIdx.z, c = blockIdx.y, q0 = blockIdx.x*64;
  const int tid = threadIdx.x;
  const int* wsI = (const int*)(ws + OFF_INT);
  const int n = wsI[c], m = T + n;
  const int* idxc = wsI + C + c*MAXN;
  const float* cf = ws + OFF_CLSF + c*8;
  const float sqs = cf[5], sqa = cf[6];
  const float gmcv = ws[OFF_GMC + p*C + c];
  const float mmv  = ws[OFF_MM  + p*C + c];
  const float* Gmp = ws + OFF_GM + (size_t)p*T*C;
  const float* SQp = ws + OFF_SQ + (size_t)p*T*NQ;
  const float* gqp = ws + OFF_GQ + p*NQ + q0;
  const float* qnp = ws + OFF_QN + p*NQ + q0;
  const float* mqp = ws + OFF_MQ + ((size_t)(p*C + c))*NQ + q0;
  const float* Wb  = ws + OFF_W + (size_t)(p*C + c)*PACKA;

  // E build; rows >= m zero-padded
  for (int lin = tid; lin < MMAX*64; lin += 256){
    int j = lin >> 6, ql = lin & 63;
    float v = 0.f;
    if (j < T){
      v = sqs*(Gmp[j*C + c] - SQp[j*NQ + q0 + ql] - gmcv + gqp[ql]);
    } else if (j < m){
      int u = idxc[j - T];
      v = sqa*(Gmp[u*C + c] - SQp[u*NQ + q0 + ql] - mmv + mqp[ql]);
    }
    E[j][ql] = v;
  }
  __syncthreads();

  const int rw = tid >> 5;          // 0..7: row group
  const int q2 = (tid & 31) * 2;    // 2 consecutive queries
  float ss0 = 0.f, ss1 = 0.f;

  #pragma unroll 1
  for (int ph = 0; ph < MMAX/NB; ++ph){
    const int k0 = ph*NB;
    const int r0 = k0 + rw;
    const int r1 = r0 + 8;
    const float* w0 = Wb + rowS(r0);
    const float* w1 = Wb + rowS(r1);
    float a00 = 0.f, a01 = 0.f, a10 = 0.f, a11 = 0.f;
    for (int k = 0; k < k0; k += 4){
      float4 wa = *(const float4*)(w0 + k);
      float4 wb = *(const float4*)(w1 + k);
      float2 e0 = *(const float2*)&E[k  ][q2];
      float2 e1 = *(const float2*)&E[k+1][q2];
      float2 e2 = *(const float2*)&E[k+2][q2];
      float2 e3 = *(const float2*)&E[k+3][q2];
      a00 += wa.x*e0.x + wa.y*e1.x + wa.z*e2.x + wa.w*e3.x;
      a01 += wa.x*e0.y + wa.y*e1.y + wa.z*e2.y + wa.w*e3.y;
      a10 += wb.x*e0.x + wb.y*e1.x + wb.z*e2.x + wb.w*e3.x;
      a11 += wb.x*e0.y + wb.y*e1.y + wb.z*e2.y + wb.w*e3.y;
    }
    R[rw][q2]     = E[r0][q2]   - a00;
    R[rw][q2+1]   = E[r0][q2+1] - a01;
    R[rw+8][q2]   = E[r1][q2]   - a10;
    R[rw+8][q2+1] = E[r1][q2+1] - a11;
    __syncthreads();
    // diag solve: z = Dinv * R for rows rw and rw+8 (Dinv rows zero for r >= m)
    {
      const float* d0 = w0 + k0;
      float z0 = 0.f, z1 = 0.f;
      for (int j = 0; j <= rw; ++j){
        float dv = d0[j];
        z0 += dv*R[j][q2]; z1 += dv*R[j][q2+1];
      }
      ss0 += z0*z0; ss1 += z1*z1;
      E[r0][q2] = z0; E[r0][q2+1] = z1;
      const float* d1 = w1 + k0;
      float y0 = 0.f, y1 = 0.f;
      for (int j = 0; j <= rw+8; ++j){
        float dv = d1[j];
        y0 += dv*R[j][q2]; y1 += dv*R[j][q2+1];
      }
      ss0 += y0*y0; ss1 += y1*y1;
      E[r1][q2] = y0; E[r1][q2+1] = y1;
    }
    __syncthreads();
  }

  // reduce ||z||^2 over the 8 row-groups per query
  R[rw][q2]   = ss0;
  R[rw][q2+1] = ss1;
  __syncthreads();
  if (tid < 64){
    int q = tid;
    float tt = 0.f;
    #pragma unroll
    for (int j = 0; j < 8; ++j) tt += R[j][q];
    float quad = mmv - 2.f*mqp[q] + qnp[q] - tt;
    ws[OFF_QUAD + ((size_t)p*NQ + q0 + q)*C + c] = quad;
  }
}

// ---------------- logits: mean over p ----------------
__global__ void k_logits(const float* ws, float* out){
  int lin = blockIdx.x*256 + threadIdx.x;
  if (lin < QL){
    float s = 0.f;
    for (int p = 0; p < P; ++p) s += ws[OFF_QUAD + (size_t)p*NQ*C + lin];
    out[lin] = -s * (1.0f/P);
  }
}

extern "C" void kernel_launch(void* const* d_in, const int* in_sizes, int n_in,
                              void* d_out, int out_size, void* d_ws, size_t ws_size,
                              hipStream_t stream){
  const float* X   = (const float*)d_in[0];
  const int*   lab = (const int*)d_in[1];
  const float* Qf  = (const float*)d_in[2];
  float* out = (float*)d_out;
  float* ws  = (float*)d_ws;

  k_setup <<<1, 64, 0, stream>>>(lab, ws);
  k_gram  <<<dim3(7,7,P),  dim3(16,16), 0, stream>>>(X, ws);
  k_pstats<<<P, 256, 0, stream>>>(ws);
  k_means <<<P*C, 256, 0, stream>>>(X, ws, out);
  k_sq    <<<dim3(7,16,P), dim3(16,16), 0, stream>>>(X, Qf, ws);
  k_qstats<<<dim3(4,P), 256, 0, stream>>>(ws);
  k_qnorm <<<(P*NQ)/4, 256, 0, stream>>>(Qf, ws);
  k_factor<<<P*C, 256, 0, stream>>>(ws);
  k_apply <<<dim3(16,C,P), 256, 0, stream>>>(ws);
  k_logits<<<QL/256, 256, 0, stream>>>(ws, out);
}

// Round 5
// 1381.291 us; speedup vs baseline: 1.3822x; 1.2544x over previous
//
#include <hip/hip_runtime.h>

// Problem constants (fixed by the reference)
#define P 8
#define T 200
#define C 20
#define F 512
#define NQ 1024
#define MAXN 40                    // max samples per class we support (true ~10±4)
#define MMAX (T + MAXN)            // 240
#define PACK ((MMAX*(MMAX+1))/2)   // 28920 packed lower-tri floats (LDS layout in k_factor)
#define PACKA 29280                // row-padded-to-4 packed layout (global W layout) = rowS(MMAX)
#define QL (NQ*C)                  // 20480 logits
#define NB 16                      // Cholesky panel width

// Workspace layout (float offsets)
enum : int {
  OFF_G    = 0,                       // P*T*T      = 320000
  OFF_SQ   = OFF_G   + P*T*T,         // P*T*NQ     = 1638400
  OFF_G1   = OFF_SQ  + P*T*NQ,        // P*T
  OFF_GG   = OFF_G1  + P*T,           // P
  OFF_GM   = OFF_GG  + P,             // P*T*C
  OFF_GMC  = OFF_GM  + P*T*C,         // P*C
  OFF_MM   = OFF_GMC + P*C,           // P*C
  OFF_GQ   = OFF_MM  + P*C,           // P*NQ
  OFF_QN   = OFF_GQ  + P*NQ,          // P*NQ
  OFF_MQ   = OFF_QN  + P*NQ,          // P*C*NQ
  OFF_W    = OFF_MQ  + P*C*NQ,        // P*C*PACKA : packed FULL INVERSE W=L^-1, rows>=m zeroed
  OFF_QUAD = OFF_W   + P*C*PACKA,     // P*NQ*C
  OFF_CLSF = OFF_QUAD+ P*NQ*C,        // C*8 scalars
  OFF_INT  = OFF_CLSF+ C*8            // int region: counts[C], idx[C*MAXN]
};

__device__ __forceinline__ int offr(int i){ return (i*(i+1))>>1; }

// 4-aligned row-padded packed layout: row i at rowS(i), length padded to mult of 4.
__device__ __forceinline__ int rowS(int i){
  int a = i >> 2, r = i & 3;
  return 8*a*(a+1) + 4*r*(a+1);
}

// flat packed index e -> row i (lower triangle, row-packed, offr layout)
__device__ __forceinline__ int row_of(int e){
  int i = (int)((sqrtf(8.f*(float)e + 1.f) - 1.f) * 0.5f);
  while (offr(i+1) <= e) ++i;
  while (offr(i) > e) --i;
  return i;
}

// ---------------- setup: counts, per-class index lists, scalars ----------------
__global__ void k_setup(const int* lab, float* ws){
  int c = threadIdx.x;
  if (c >= C) return;
  int* wsI = (int*)(ws + OFF_INT);
  int n = 0;
  for (int t = 0; t < T; ++t){
    if (lab[t] == c){ if (n < MAXN) wsI[C + c*MAXN + n] = t; ++n; }
  }
  if (n > MAXN) n = MAXN;
  wsI[c] = n;
  float nf    = (float)n;
  float nsafe = fmaxf(nf, 1.0f);
  float dn    = fmaxf(nf - 1.0f, 1.0f);
  float lam   = nsafe / (nsafe + 1.0f);
  float sv    = (1.0f - lam) / (float)(T - 1);
  float av    = lam / dn;
  float* cf = ws + OFF_CLSF + c*8;
  cf[0] = nsafe; cf[1] = dn; cf[2] = lam; cf[3] = sv; cf[4] = av;
  cf[5] = sqrtf(sv); cf[6] = sqrtf(av); cf[7] = 0.0f;
}

// ---------------- G = X X^T per p (200x200) ----------------
__global__ __launch_bounds__(256) void k_gram(const float* X, float* ws){
  __shared__ float Xi[32][33];
  __shared__ float Xj[32][33];
  const int p = blockIdx.z, i0 = blockIdx.y*32, j0 = blockIdx.x*32;
  const int tx = threadIdx.x, ty = threadIdx.y;
  const int tid = ty*16 + tx;
  const float* Xp = X + (size_t)p*T*F;
  float acc[2][2] = {{0.f,0.f},{0.f,0.f}};
  for (int kb = 0; kb < F; kb += 32){
    for (int e = tid; e < 32*32; e += 256){
      int r = e >> 5, kk = e & 31;
      Xi[r][kk] = (i0+r < T) ? Xp[(i0+r)*F + kb+kk] : 0.f;
      Xj[r][kk] = (j0+r < T) ? Xp[(j0+r)*F + kb+kk] : 0.f;
    }
    __syncthreads();
    for (int kk = 0; kk < 32; ++kk){
      float a0 = Xi[2*ty][kk],   a1 = Xi[2*ty+1][kk];
      float b0 = Xj[2*tx][kk],   b1 = Xj[2*tx+1][kk];
      acc[0][0] += a0*b0; acc[0][1] += a0*b1;
      acc[1][0] += a1*b0; acc[1][1] += a1*b1;
    }
    __syncthreads();
  }
  float* Gp = ws + OFF_G + (size_t)p*T*T;
  for (int a = 0; a < 2; ++a)
    for (int b = 0; b < 2; ++b){
      int i = i0 + 2*ty + a, j = j0 + 2*tx + b;
      if (i < T && j < T) Gp[i*T + j] = acc[a][b];
    }
}

// ---------------- per-p stats: g1, gg, Gm, gmc, mm ----------------
__global__ __launch_bounds__(256) void k_pstats(float* ws){
  const int p = blockIdx.x, tid = threadIdx.x;
  const int* wsI = (const int*)(ws + OFF_INT);
  const float* Gp = ws + OFF_G + (size_t)p*T*T;
  float* g1 = ws + OFF_G1 + p*T;
  for (int t = tid; t < T; t += 256){
    float s = 0.f;
    for (int u = 0; u < T; ++u) s += Gp[t*T + u];
    g1[t] = s * (1.0f/T);
  }
  __syncthreads();
  if (tid == 0){
    float s = 0.f;
    for (int t = 0; t < T; ++t) s += g1[t];
    ws[OFF_GG + p] = s * (1.0f/T);
  }
  float* Gm = ws + OFF_GM + (size_t)p*T*C;
  for (int t = tid; t < T; t += 256){
    for (int c = 0; c < C; ++c){
      int n = wsI[c];
      const int* idxc = wsI + C + c*MAXN;
      float s = 0.f;
      for (int j = 0; j < n; ++j) s += Gp[t*T + idxc[j]];
      Gm[t*C + c] = s / ws[OFF_CLSF + c*8];
    }
  }
  __syncthreads();
  if (tid < C){
    int c = tid, n = wsI[c];
    const int* idxc = wsI + C + c*MAXN;
    float s = 0.f;
    for (int t = 0; t < T; ++t) s += Gm[t*C + c];
    ws[OFF_GMC + p*C + c] = s * (1.0f/T);
    float s2 = 0.f;
    for (int j = 0; j < n; ++j) s2 += Gm[idxc[j]*C + c];
    ws[OFF_MM + p*C + c] = s2 / ws[OFF_CLSF + c*8];
  }
}

// ---------------- class means -> output part 2 ----------------
__global__ __launch_bounds__(256) void k_means(const float* X, const float* ws, float* out){
  const int blk = blockIdx.x, p = blk / C, c = blk % C;
  const int* wsI = (const int*)(ws + OFF_INT);
  const int n = wsI[c];
  const int* idxc = wsI + C + c*MAXN;
  const float nf = ws[OFF_CLSF + c*8];
  const float* Xp = X + (size_t)p*T*F;
  float* o = out + QL + (size_t)(p*C + c)*F;
  for (int f = threadIdx.x; f < F; f += 256){
    float s = 0.f;
    for (int j = 0; j < n; ++j) s += Xp[idxc[j]*F + f];
    o[f] = s / nf;
  }
}

// ---------------- SQ = X Q^T per p (200x1024) ----------------
__global__ __launch_bounds__(256) void k_sq(const float* X, const float* Qf, float* ws){
  __shared__ float Xt[32][33];
  __shared__ float Qt[64][33];
  const int p = blockIdx.z, t0 = blockIdx.x*32, q0 = blockIdx.y*64;
  const int tx = threadIdx.x, ty = threadIdx.y;
  const int tid = ty*16 + tx;
  const float* Xp = X  + (size_t)p*T*F;
  const float* Qp = Qf + (size_t)p*NQ*F;
  float acc[2][4] = {};
  for (int kb = 0; kb < F; kb += 32){
    for (int e = tid; e < 32*32; e += 256){
      int r = e >> 5, kk = e & 31;
      Xt[r][kk] = (t0+r < T) ? Xp[(t0+r)*F + kb+kk] : 0.f;
    }
    for (int e = tid; e < 64*32; e += 256){
      int r = e >> 5, kk = e & 31;
      Qt[r][kk] = Qp[(q0+r)*F + kb+kk];
    }
    __syncthreads();
    for (int kk = 0; kk < 32; ++kk){
      float a0 = Xt[2*ty][kk], a1 = Xt[2*ty+1][kk];
      float b0 = Qt[4*tx][kk], b1 = Qt[4*tx+1][kk], b2 = Qt[4*tx+2][kk], b3 = Qt[4*tx+3][kk];
      acc[0][0] += a0*b0; acc[0][1] += a0*b1; acc[0][2] += a0*b2; acc[0][3] += a0*b3;
      acc[1][0] += a1*b0; acc[1][1] += a1*b1; acc[1][2] += a1*b2; acc[1][3] += a1*b3;
    }
    __syncthreads();
  }
  float* SQp = ws + OFF_SQ + (size_t)p*T*NQ;
  for (int a = 0; a < 2; ++a){
    int t = t0 + 2*ty + a;
    if (t < T)
      for (int b = 0; b < 4; ++b)
        SQp[t*NQ + q0 + 4*tx + b] = acc[a][b];
  }
}

// ---------------- per-q stats: gq, mq ----------------
__global__ __launch_bounds__(256) void k_qstats(float* ws){
  const int p = blockIdx.y;
  const int q = blockIdx.x*256 + threadIdx.x;
  const int* wsI = (const int*)(ws + OFF_INT);
  const float* SQp = ws + OFF_SQ + (size_t)p*T*NQ;
  float s = 0.f;
  for (int t = 0; t < T; ++t) s += SQp[t*NQ + q];
  ws[OFF_GQ + p*NQ + q] = s * (1.0f/T);
  for (int c = 0; c < C; ++c){
    int n = wsI[c];
    const int* idxc = wsI + C + c*MAXN;
    float sc = 0.f;
    for (int j = 0; j < n; ++j) sc += SQp[idxc[j]*NQ + q];
    ws[OFF_MQ + ((size_t)(p*C + c))*NQ + q] = sc / ws[OFF_CLSF + c*8];
  }
}

// ---------------- qn = ||q||^2, one wave per row, float4 + shuffle reduce ----------------
__global__ __launch_bounds__(256) void k_qnorm(const float* Qf, float* ws){
  const int row  = blockIdx.x*4 + (threadIdx.x >> 6);   // row = p*NQ + q
  const int lane = threadIdx.x & 63;
  const float4* q4p = (const float4*)(Qf + (size_t)row*F);
  float4 v0 = q4p[lane];
  float4 v1 = q4p[lane + 64];
  float s = v0.x*v0.x + v0.y*v0.y + v0.z*v0.z + v0.w*v0.w
          + v1.x*v1.x + v1.y*v1.y + v1.z*v1.z + v1.w*v1.w;
  for (int off = 32; off; off >>= 1) s += __shfl_down(s, off, 64);
  if (lane == 0) ws[OFF_QN + row] = s;
}

// ---------------- build M, blocked Cholesky, FULL blocked triangular inversion
//                  W = L^-1 in LDS; store packed (rowS layout), rows>=m zeroed ----------------
__global__ __launch_bounds__(256) void k_factor(float* ws){
  __shared__ float Lp[PACK];            // packed lower triangle, 115.7 KB
  __shared__ float Pn[MMAX+4][NB+1];    // panel buffer / S buffer, 16.6 KB
  const int blk = blockIdx.x, p = blk / C, c = blk % C;
  const int tid = threadIdx.x;
  const int* wsI = (const int*)(ws + OFF_INT);
  const int n = wsI[c];
  const int m = T + n;
  const int* idxc = wsI + C + c*MAXN;
  const float* cf = ws + OFF_CLSF + c*8;
  const float sv = cf[3], av = cf[4], sqsa = cf[5]*cf[6];
  const float* Gp  = ws + OFF_G  + (size_t)p*T*T;
  const float* g1p = ws + OFF_G1 + p*T;
  const float  ggv = ws[OFF_GG + p];
  const float* Gmp = ws + OFF_GM + (size_t)p*T*C;
  const float gmcv = ws[OFF_GMC + p*C + c];
  const float mmv  = ws[OFF_MM  + p*C + c];
  const int tot = (m*(m+1)) >> 1;

  // ---- build M packed; zero-fill tail rows so all later loops are uniform ----
  for (int e = tid; e < tot; e += 256){
    int i = row_of(e);
    int j = e - offr(i);
    float v;
    if (i < T){
      v = sv*(Gp[i*T + j] - g1p[i] - g1p[j] + ggv);
      if (j == i) v += 1.0f;
    } else {
      int ua = idxc[i - T];
      if (j < T){
        v = sqsa*(Gp[ua*T + j] - Gmp[j*C + c] - g1p[ua] + gmcv);
      } else {
        int ub = idxc[j - T];
        v = av*(Gp[ua*T + ub] - Gmp[ua*C + c] - Gmp[ub*C + c] + mmv);
        if (j == i) v += 1.0f;
      }
    }
    Lp[e] = v;
  }
  for (int e = tot + tid; e < PACK; e += 256) Lp[e] = 0.f;
  __syncthreads();

  // ---- blocked right-looking Cholesky (diag 16x16 blocks inverted in place) ----
  for (int k0 = 0; k0 < m; k0 += NB){
    const int kb = min(NB, m - k0);
    const int rows = m - k0;
    const int rowsP = (rows + 3) & ~3;
    for (int e = tid; e < rowsP*NB; e += 256){
      int r = e >> 4, cl = e & 15;
      float v = 0.f;
      if (r < rows && cl < kb && (r >= NB || cl <= r)) v = Lp[offr(k0+r) + k0 + cl];
      Pn[r][cl] = v;
    }
    __syncthreads();
    for (int jl = 0; jl < kb; ++jl){
      float d = Pn[jl][jl];
      float inv = 1.0f / sqrtf(d);
      __syncthreads();
      for (int i = jl + tid; i < rows; i += 256) Pn[i][jl] *= inv;
      __syncthreads();
      for (int i = jl + 1 + tid; i < rows; i += 256){
        float pij = Pn[i][jl];
        for (int cl = jl + 1; cl < kb; ++cl) Pn[i][cl] -= pij * Pn[cl][jl];
      }
      __syncthreads();
    }
    if (tid < kb){
      int j = tid;
      float x[NB];
      x[j] = 1.0f / Pn[j][j];
      for (int i = j + 1; i < kb; ++i){
        float s = 0.f;
        for (int k = j; k < i; ++k) s += Pn[i][k] * x[k];
        x[i] = -s / Pn[i][i];
      }
      for (int i = j; i < kb; ++i) Lp[offr(k0+i) + k0 + j] = x[i];
    }
    for (int e = tid; e < (rows - kb)*NB; e += 256){
      int r = kb + (e >> 4), cl = e & 15;
      if (cl < kb) Lp[offr(k0+r) + k0 + cl] = Pn[r][cl];
    }
    const int rs = rows - kb;
    if (rs > 0){
      const int nt4 = (rs + 3) >> 2;
      const int ntile = (nt4*(nt4+1)) >> 1;
      for (int e = tid; e < ntile; e += 256){
        int ti = row_of(e);
        int tj = e - offr(ti);
        int i0 = kb + 4*ti, j0 = kb + 4*tj;
        float acc[4][4] = {};
        #pragma unroll 4
        for (int k = 0; k < NB; ++k){
          float a0 = Pn[i0][k], a1 = Pn[i0+1][k], a2 = Pn[i0+2][k], a3 = Pn[i0+3][k];
          float b0 = Pn[j0][k], b1 = Pn[j0+1][k], b2 = Pn[j0+2][k], b3 = Pn[j0+3][k];
          acc[0][0] += a0*b0; acc[0][1] += a0*b1; acc[0][2] += a0*b2; acc[0][3] += a0*b3;
          acc[1][0] += a1*b0; acc[1][1] += a1*b1; acc[1][2] += a1*b2; acc[1][3] += a1*b3;
          acc[2][0] += a2*b0; acc[2][1] += a2*b1; acc[2][2] += a2*b2; acc[2][3] += a2*b3;
          acc[3][0] += a3*b0; acc[3][1] += a3*b1; acc[3][2] += a3*b2; acc[3][3] += a3*b3;
        }
        #pragma unroll
        for (int u = 0; u < 4; ++u){
          int gi = k0 + i0 + u;
          if (gi < m){
            int og = offr(gi);
            #pragma unroll
            for (int v2 = 0; v2 < 4; ++v2){
              int gj = k0 + j0 + v2;
              if (gj <= gi) Lp[og + gj] -= acc[u][v2];
            }
          }
        }
      }
    }
    __syncthreads();
  }

  // ---- full triangular inversion: X = L^-1 in place.
  //      Ascending block-rows I: S = L[I,0:i0] * X[0:i0,0:i0]; X[I,0:i0] = -Dinv_I * S.
  //      Zero-padded rows make all bounds uniform (MMAX-based). ----
  float* Sb = &Pn[0][0];   // 16 x (stride 225) = 3600 floats <= 4148 available
  for (int I = 1; I < MMAX/NB; ++I){
    const int i0 = I*NB;
    const int nct = i0 >> 2;
    const int rt = tid & 3, ct = tid >> 2;
    const int r0 = i0 + rt*4;
    const int o0 = offr(r0), o1 = offr(r0+1), o2 = offr(r0+2), o3 = offr(r0+3);
    const int j0 = ct*4;
    if (tid < 4*nct){
      float acc[4][4] = {};
      // head: k = j0..j0+3 (X upper-zero mask)
      #pragma unroll
      for (int kk = 0; kk < 4; ++kk){
        const int k = j0 + kk;
        const int ok = offr(k);
        const float l0 = Lp[o0+k], l1 = Lp[o1+k], l2 = Lp[o2+k], l3 = Lp[o3+k];
        #pragma unroll
        for (int v = 0; v < 4; ++v){
          const float xv = (j0 + v <= k) ? Lp[ok + j0 + v] : 0.f;
          acc[0][v] += l0*xv; acc[1][v] += l1*xv; acc[2][v] += l2*xv; acc[3][v] += l3*xv;
        }
      }
      for (int k = j0 + 4; k < i0; ++k){
        const int ok = offr(k) + j0;
        const float l0 = Lp[o0+k], l1 = Lp[o1+k], l2 = Lp[o2+k], l3 = Lp[o3+k];
        const float x0 = Lp[ok], x1 = Lp[ok+1], x2 = Lp[ok+2], x3 = Lp[ok+3];
        acc[0][0] += l0*x0; acc[0][1] += l0*x1; acc[0][2] += l0*x2; acc[0][3] += l0*x3;
        acc[1][0] += l1*x0; acc[1][1] += l1*x1; acc[1][2] += l1*x2; acc[1][3] += l1*x3;
        acc[2][0] += l2*x0; acc[2][1] += l2*x1; acc[2][2] += l2*x2; acc[2][3] += l2*x3;
        acc[3][0] += l3*x0; acc[3][1] += l3*x1; acc[3][2] += l3*x2; acc[3][3] += l3*x3;
      }
      #pragma unroll
      for (int u = 0; u < 4; ++u)
        #pragma unroll
        for (int v = 0; v < 4; ++v)
          Sb[(rt*4+u)*225 + j0 + v] = acc[u][v];
    }
    __syncthreads();
    if (tid < 4*nct){
      float acc[4][4] = {};
      for (int s = 0; s < rt*4 + 4; ++s){
        const float d0 = (s <= rt*4    ) ? Lp[o0 + i0 + s] : 0.f;
        const float d1 = (s <= rt*4 + 1) ? Lp[o1 + i0 + s] : 0.f;
        const float d2 = (s <= rt*4 + 2) ? Lp[o2 + i0 + s] : 0.f;
        const float d3 = Lp[o3 + i0 + s];
        const float s0 = Sb[s*225 + j0], s1 = Sb[s*225 + j0 + 1];
        const float s2 = Sb[s*225 + j0 + 2], s3 = Sb[s*225 + j0 + 3];
        acc[0][0] += d0*s0; acc[0][1] += d0*s1; acc[0][2] += d0*s2; acc[0][3] += d0*s3;
        acc[1][0] += d1*s0; acc[1][1] += d1*s1; acc[1][2] += d1*s2; acc[1][3] += d1*s3;
        acc[2][0] += d2*s0; acc[2][1] += d2*s1; acc[2][2] += d2*s2; acc[2][3] += d2*s3;
        acc[3][0] += d3*s0; acc[3][1] += d3*s1; acc[3][2] += d3*s2; acc[3][3] += d3*s3;
      }
      #pragma unroll
      for (int v = 0; v < 4; ++v){
        Lp[o0 + j0 + v] = -acc[0][v];
        Lp[o1 + j0 + v] = -acc[1][v];
        Lp[o2 + j0 + v] = -acc[2][v];
        Lp[o3 + j0 + v] = -acc[3][v];
      }
    }
    __syncthreads();
  }

  // ---- store packed W = L^-1 into rowS layout; zero tail rows (>= m) ----
  float* Wg = ws + OFF_W + (size_t)blk * PACKA;
  for (int e = tid; e < tot; e += 256){
    int i = row_of(e);
    int j = e - offr(i);
    Wg[rowS(i) + j] = Lp[e];
  }
  const int z0 = rowS(m);
  for (int e = z0 + tid; e < PACKA; e += 256) Wg[e] = 0.f;
}

// ---------------- apply: z = W*e as tiled lower-tri GEMM; quad = ||d||^2 - ||z||^2.
//                  64-row tiles, 32-col W tiles staged to LDS (double-buffered,
//                  transposed), 4x4 register tiles, squares accumulated in regs ----------------
__global__ __launch_bounds__(256) void k_apply(float* ws){
  __shared__ float E[256][64];        // e (zero-padded to 256 rows); 64 KB
  __shared__ float Wt[2][32][64];     // W tile, [k][r] col-major; 16 KB (reused as reduce buf)
  const int p = blockIdx.z, c = blockIdx.y, q0 = blockIdx.x*64;
  const int tid = threadIdx.x;
  const int* wsI = (const int*)(ws + OFF_INT);
  const int n = wsI[c], m = T + n;
  const int* idxc = wsI + C + c*MAXN;
  const float* cf = ws + OFF_CLSF + c*8;
  const float sqs = cf[5], sqa = cf[6];
  const float gmcv = ws[OFF_GMC + p*C + c];
  const float mmv  = ws[OFF_MM  + p*C + c];
  const float* Gmp = ws + OFF_GM + (size_t)p*T*C;
  const float* SQp = ws + OFF_SQ + (size_t)p*T*NQ;
  const float* gqp = ws + OFF_GQ + p*NQ + q0;
  const float* qnp = ws + OFF_QN + p*NQ + q0;
  const float* mqp = ws + OFF_MQ + ((size_t)(p*C + c))*NQ + q0;
  const float* Wg  = ws + OFF_W + (size_t)(p*C + c)*PACKA;

  // ---- build E rows 0..255 (zero pad >= m) ----
  for (int lin = tid; lin < 256*64; lin += 256){
    int j = lin >> 6, ql = lin & 63;
    float v = 0.f;
    if (j < T){
      v = sqs*(Gmp[j*C + c] - SQp[j*NQ + q0 + ql] - gmcv + gqp[ql]);
    } else if (j < m){
      int u = idxc[j - T];
      v = sqa*(Gmp[u*C + c] - SQp[u*NQ + q0 + ql] - mmv + mqp[ql]);
    }
    E[j][ql] = v;
  }
  __syncthreads();

  const int rg4 = (tid >> 4) * 4;     // 4 rows within row-tile
  const int cg4 = (tid & 15) * 4;     // 4 query columns
  const int sr  = tid >> 2;           // staging: row within tile (0..63)
  const int sk  = (tid & 3) * 8;      // staging: 8 cols starting here
  float ss0 = 0.f, ss1 = 0.f, ss2 = 0.f, ss3 = 0.f;

  for (int R = 0; R < 4; ++R){
    const int i0 = R*64;
    const int nct = 2*R + 2;
    // stage tile ct=0 into buf 0
    {
      const int i = i0 + sr, j0s = sk;      // ct=0 -> col base 0
      float v[8] = {};
      if (i < MMAX && j0s <= i){
        const float* wr = Wg + rowS(i) + j0s;
        if (j0s + 7 <= i){
          float4 a = *(const float4*)wr, b = *(const float4*)(wr+4);
          v[0]=a.x; v[1]=a.y; v[2]=a.z; v[3]=a.w; v[4]=b.x; v[5]=b.y; v[6]=b.z; v[7]=b.w;
        } else {
          #pragma unroll
          for (int u = 0; u < 8; ++u) if (j0s + u <= i) v[u] = wr[u];
        }
      }
      #pragma unroll
      for (int u = 0; u < 8; ++u) Wt[0][sk+u][sr] = v[u];
    }
    __syncthreads();

    float acc[4][4] = {};
    for (int ct = 0; ct < nct; ++ct){
      const int buf = ct & 1;
      if (ct + 1 < nct){   // prefetch next tile into other buffer
        const int i = i0 + sr, j0s = (ct+1)*32 + sk;
        float v[8] = {};
        if (i < MMAX && j0s <= i){
          const float* wr = Wg + rowS(i) + j0s;
          if (j0s + 7 <= i){
            float4 a = *(const float4*)wr, b = *(const float4*)(wr+4);
            v[0]=a.x; v[1]=a.y; v[2]=a.z; v[3]=a.w; v[4]=b.x; v[5]=b.y; v[6]=b.z; v[7]=b.w;
          } else {
            #pragma unroll
            for (int u = 0; u < 8; ++u) if (j0s + u <= i) v[u] = wr[u];
          }
        }
        #pragma unroll
        for (int u = 0; u < 8; ++u) Wt[buf^1][sk+u][sr] = v[u];
      }
      const int j0 = ct*32;
      #pragma unroll 4
      for (int k = 0; k < 32; ++k){
        const float4 w = *(const float4*)&Wt[buf][k][rg4];
        const float4 e = *(const float4*)&E[j0+k][cg4];
        acc[0][0] += w.x*e.x; acc[0][1] += w.x*e.y; acc[0][2] += w.x*e.z; acc[0][3] += w.x*e.w;
        acc[1][0] += w.y*e.x; acc[1][1] += w.y*e.y; acc[1][2] += w.y*e.z; acc[1][3] += w.y*e.w;
        acc[2][0] += w.z*e.x; acc[2][1] += w.z*e.y; acc[2][2] += w.z*e.z; acc[2][3] += w.z*e.w;
        acc[3][0] += w.w*e.x; acc[3][1] += w.w*e.y; acc[3][2] += w.w*e.z; acc[3][3] += w.w*e.w;
      }
      __syncthreads();
    }
    // accumulate ||z||^2 contributions for this row-tile
    ss0 += acc[0][0]*acc[0][0] + acc[1][0]*acc[1][0] + acc[2][0]*acc[2][0] + acc[3][0]*acc[3][0];
    ss1 += acc[0][1]*acc[0][1] + acc[1][1]*acc[1][1] + acc[2][1]*acc[2][1] + acc[3][1]*acc[3][1];
    ss2 += acc[0][2]*acc[0][2] + acc[1][2]*acc[1][2] + acc[2][2]*acc[2][2] + acc[3][2]*acc[3][2];
    ss3 += acc[0][3]*acc[0][3] + acc[1][3]*acc[1][3] + acc[2][3]*acc[2][3] + acc[3][3]*acc[3][3];
  }

  // ---- reduce over the 16 row-groups per query (reuse Wt as buffer) ----
  float* Rb = &Wt[0][0][0];
  const int rg = tid >> 4;
  Rb[rg*64 + cg4 + 0] = ss0;
  Rb[rg*64 + cg4 + 1] = ss1;
  Rb[rg*64 + cg4 + 2] = ss2;
  Rb[rg*64 + cg4 + 3] = ss3;
  __syncthreads();
  if (tid < 64){
    float tt = 0.f;
    #pragma unroll
    for (int g = 0; g < 16; ++g) tt += Rb[g*64 + tid];
    float quad = mmv - 2.f*mqp[tid] + qnp[tid] - tt;
    ws[OFF_QUAD + ((size_t)p*NQ + q0 + tid)*C + c] = quad;
  }
}

// ---------------- logits: mean over p ----------------
__global__ void k_logits(const float* ws, float* out){
  int lin = blockIdx.x*256 + threadIdx.x;
  if (lin < QL){
    float s = 0.f;
    for (int p = 0; p < P; ++p) s += ws[OFF_QUAD + (size_t)p*NQ*C + lin];
    out[lin] = -s * (1.0f/P);
  }
}

extern "C" void kernel_launch(void* const* d_in, const int* in_sizes, int n_in,
                              void* d_out, int out_size, void* d_ws, size_t ws_size,
                              hipStream_t stream){
  const float* X   = (const float*)d_in[0];
  const int*   lab = (const int*)d_in[1];
  const float* Qf  = (const float*)d_in[2];
  float* out = (float*)d_out;
  float* ws  = (float*)d_ws;

  k_setup <<<1, 64, 0, stream>>>(lab, ws);
  k_gram  <<<dim3(7,7,P),  dim3(16,16), 0, stream>>>(X, ws);
  k_pstats<<<P, 256, 0, stream>>>(ws);
  k_means <<<P*C, 256, 0, stream>>>(X, ws, out);
  k_sq    <<<dim3(7,16,P), dim3(16,16), 0, stream>>>(X, Qf, ws);
  k_qstats<<<dim3(4,P), 256, 0, stream>>>(ws);
  k_qnorm <<<(P*NQ)/4, 256, 0, stream>>>(Qf, ws);
  k_factor<<<P*C, 256, 0, stream>>>(ws);
  k_apply <<<dim3(16,C,P), 256, 0, stream>>>(ws);
  k_logits<<<QL/256, 256, 0, stream>>>(ws, out);
}

// Round 6
// 948.045 us; speedup vs baseline: 2.0139x; 1.4570x over previous
//
#include <hip/hip_runtime.h>

// Problem constants (fixed by the reference)
#define P 8
#define T 200
#define C 20
#define F 512
#define NQ 1024
#define MAXN 40                    // max samples per class we support (true ~10±4)
#define MMAX (T + MAXN)            // 240
#define PACK ((MMAX*(MMAX+1))/2)   // 28920 packed lower-tri floats (LDS layout in k_factor)
#define PACKA 29280                // row-padded-to-4 packed layout (global W layout) = rowS(MMAX)
#define QL (NQ*C)                  // 20480 logits
#define NB 16                      // Cholesky panel width
#define NTF 512                    // k_factor block size (8 waves)

// Workspace layout (float offsets)
enum : int {
  OFF_G    = 0,                       // P*T*T      = 320000
  OFF_SQ   = OFF_G   + P*T*T,         // P*T*NQ     = 1638400
  OFF_G1   = OFF_SQ  + P*T*NQ,        // P*T
  OFF_GG   = OFF_G1  + P*T,           // P
  OFF_GM   = OFF_GG  + P,             // P*T*C
  OFF_GMC  = OFF_GM  + P*T*C,         // P*C
  OFF_MM   = OFF_GMC + P*C,           // P*C
  OFF_GQ   = OFF_MM  + P*C,           // P*NQ
  OFF_QN   = OFF_GQ  + P*NQ,          // P*NQ
  OFF_MQ   = OFF_QN  + P*NQ,          // P*C*NQ
  OFF_W    = OFF_MQ  + P*C*NQ,        // P*C*PACKA : packed FULL INVERSE W=L^-1, rows>=m zeroed
  OFF_QUAD = OFF_W   + P*C*PACKA,     // P*NQ*C
  OFF_CLSF = OFF_QUAD+ P*NQ*C,        // C*8 scalars
  OFF_INT  = OFF_CLSF+ C*8            // int region: counts[C], idx[C*MAXN]
};

__device__ __forceinline__ int offr(int i){ return (i*(i+1))>>1; }

// 4-aligned row-padded packed layout: row i at rowS(i), length padded to mult of 4.
__device__ __forceinline__ int rowS(int i){
  int a = i >> 2, r = i & 3;
  return 8*a*(a+1) + 4*r*(a+1);
}

// flat packed index e -> row i (lower triangle, row-packed, offr layout)
__device__ __forceinline__ int row_of(int e){
  int i = (int)((sqrtf(8.f*(float)e + 1.f) - 1.f) * 0.5f);
  while (offr(i+1) <= e) ++i;
  while (offr(i) > e) --i;
  return i;
}

// ---------------- setup: counts, per-class index lists, scalars ----------------
__global__ void k_setup(const int* lab, float* ws){
  int c = threadIdx.x;
  if (c >= C) return;
  int* wsI = (int*)(ws + OFF_INT);
  int n = 0;
  for (int t = 0; t < T; ++t){
    if (lab[t] == c){ if (n < MAXN) wsI[C + c*MAXN + n] = t; ++n; }
  }
  if (n > MAXN) n = MAXN;
  wsI[c] = n;
  float nf    = (float)n;
  float nsafe = fmaxf(nf, 1.0f);
  float dn    = fmaxf(nf - 1.0f, 1.0f);
  float lam   = nsafe / (nsafe + 1.0f);
  float sv    = (1.0f - lam) / (float)(T - 1);
  float av    = lam / dn;
  float* cf = ws + OFF_CLSF + c*8;
  cf[0] = nsafe; cf[1] = dn; cf[2] = lam; cf[3] = sv; cf[4] = av;
  cf[5] = sqrtf(sv); cf[6] = sqrtf(av); cf[7] = 0.0f;
}

// ---------------- G = X X^T per p (200x200) ----------------
__global__ __launch_bounds__(256) void k_gram(const float* X, float* ws){
  __shared__ float Xi[32][33];
  __shared__ float Xj[32][33];
  const int p = blockIdx.z, i0 = blockIdx.y*32, j0 = blockIdx.x*32;
  const int tx = threadIdx.x, ty = threadIdx.y;
  const int tid = ty*16 + tx;
  const float* Xp = X + (size_t)p*T*F;
  float acc[2][2] = {{0.f,0.f},{0.f,0.f}};
  for (int kb = 0; kb < F; kb += 32){
    for (int e = tid; e < 32*32; e += 256){
      int r = e >> 5, kk = e & 31;
      Xi[r][kk] = (i0+r < T) ? Xp[(i0+r)*F + kb+kk] : 0.f;
      Xj[r][kk] = (j0+r < T) ? Xp[(j0+r)*F + kb+kk] : 0.f;
    }
    __syncthreads();
    for (int kk = 0; kk < 32; ++kk){
      float a0 = Xi[2*ty][kk],   a1 = Xi[2*ty+1][kk];
      float b0 = Xj[2*tx][kk],   b1 = Xj[2*tx+1][kk];
      acc[0][0] += a0*b0; acc[0][1] += a0*b1;
      acc[1][0] += a1*b0; acc[1][1] += a1*b1;
    }
    __syncthreads();
  }
  float* Gp = ws + OFF_G + (size_t)p*T*T;
  for (int a = 0; a < 2; ++a)
    for (int b = 0; b < 2; ++b){
      int i = i0 + 2*ty + a, j = j0 + 2*tx + b;
      if (i < T && j < T) Gp[i*T + j] = acc[a][b];
    }
}

// ---------------- per-p stats: g1, gg, Gm, gmc, mm ----------------
__global__ __launch_bounds__(256) void k_pstats(float* ws){
  const int p = blockIdx.x, tid = threadIdx.x;
  const int* wsI = (const int*)(ws + OFF_INT);
  const float* Gp = ws + OFF_G + (size_t)p*T*T;
  float* g1 = ws + OFF_G1 + p*T;
  for (int t = tid; t < T; t += 256){
    float s = 0.f;
    for (int u = 0; u < T; ++u) s += Gp[t*T + u];
    g1[t] = s * (1.0f/T);
  }
  __syncthreads();
  if (tid == 0){
    float s = 0.f;
    for (int t = 0; t < T; ++t) s += g1[t];
    ws[OFF_GG + p] = s * (1.0f/T);
  }
  float* Gm = ws + OFF_GM + (size_t)p*T*C;
  for (int t = tid; t < T; t += 256){
    for (int c = 0; c < C; ++c){
      int n = wsI[c];
      const int* idxc = wsI + C + c*MAXN;
      float s = 0.f;
      for (int j = 0; j < n; ++j) s += Gp[t*T + idxc[j]];
      Gm[t*C + c] = s / ws[OFF_CLSF + c*8];
    }
  }
  __syncthreads();
  if (tid < C){
    int c = tid, n = wsI[c];
    const int* idxc = wsI + C + c*MAXN;
    float s = 0.f;
    for (int t = 0; t < T; ++t) s += Gm[t*C + c];
    ws[OFF_GMC + p*C + c] = s * (1.0f/T);
    float s2 = 0.f;
    for (int j = 0; j < n; ++j) s2 += Gm[idxc[j]*C + c];
    ws[OFF_MM + p*C + c] = s2 / ws[OFF_CLSF + c*8];
  }
}

// ---------------- class means -> output part 2 ----------------
__global__ __launch_bounds__(256) void k_means(const float* X, const float* ws, float* out){
  const int blk = blockIdx.x, p = blk / C, c = blk % C;
  const int* wsI = (const int*)(ws + OFF_INT);
  const int n = wsI[c];
  const int* idxc = wsI + C + c*MAXN;
  const float nf = ws[OFF_CLSF + c*8];
  const float* Xp = X + (size_t)p*T*F;
  float* o = out + QL + (size_t)(p*C + c)*F;
  for (int f = threadIdx.x; f < F; f += 256){
    float s = 0.f;
    for (int j = 0; j < n; ++j) s += Xp[idxc[j]*F + f];
    o[f] = s / nf;
  }
}

// ---------------- SQ = X Q^T per p (200x1024) ----------------
__global__ __launch_bounds__(256) void k_sq(const float* X, const float* Qf, float* ws){
  __shared__ float Xt[32][33];
  __shared__ float Qt[64][33];
  const int p = blockIdx.z, t0 = blockIdx.x*32, q0 = blockIdx.y*64;
  const int tx = threadIdx.x, ty = threadIdx.y;
  const int tid = ty*16 + tx;
  const float* Xp = X  + (size_t)p*T*F;
  const float* Qp = Qf + (size_t)p*NQ*F;
  float acc[2][4] = {};
  for (int kb = 0; kb < F; kb += 32){
    for (int e = tid; e < 32*32; e += 256){
      int r = e >> 5, kk = e & 31;
      Xt[r][kk] = (t0+r < T) ? Xp[(t0+r)*F + kb+kk] : 0.f;
    }
    for (int e = tid; e < 64*32; e += 256){
      int r = e >> 5, kk = e & 31;
      Qt[r][kk] = Qp[(q0+r)*F + kb+kk];
    }
    __syncthreads();
    for (int kk = 0; kk < 32; ++kk){
      float a0 = Xt[2*ty][kk], a1 = Xt[2*ty+1][kk];
      float b0 = Qt[4*tx][kk], b1 = Qt[4*tx+1][kk], b2 = Qt[4*tx+2][kk], b3 = Qt[4*tx+3][kk];
      acc[0][0] += a0*b0; acc[0][1] += a0*b1; acc[0][2] += a0*b2; acc[0][3] += a0*b3;
      acc[1][0] += a1*b0; acc[1][1] += a1*b1; acc[1][2] += a1*b2; acc[1][3] += a1*b3;
    }
    __syncthreads();
  }
  float* SQp = ws + OFF_SQ + (size_t)p*T*NQ;
  for (int a = 0; a < 2; ++a){
    int t = t0 + 2*ty + a;
    if (t < T)
      for (int b = 0; b < 4; ++b)
        SQp[t*NQ + q0 + 4*tx + b] = acc[a][b];
  }
}

// ---------------- per-q stats: gq, mq ----------------
__global__ __launch_bounds__(256) void k_qstats(float* ws){
  const int p = blockIdx.y;
  const int q = blockIdx.x*256 + threadIdx.x;
  const int* wsI = (const int*)(ws + OFF_INT);
  const float* SQp = ws + OFF_SQ + (size_t)p*T*NQ;
  float s = 0.f;
  for (int t = 0; t < T; ++t) s += SQp[t*NQ + q];
  ws[OFF_GQ + p*NQ + q] = s * (1.0f/T);
  for (int c = 0; c < C; ++c){
    int n = wsI[c];
    const int* idxc = wsI + C + c*MAXN;
    float sc = 0.f;
    for (int j = 0; j < n; ++j) sc += SQp[idxc[j]*NQ + q];
    ws[OFF_MQ + ((size_t)(p*C + c))*NQ + q] = sc / ws[OFF_CLSF + c*8];
  }
}

// ---------------- qn = ||q||^2, one wave per row, float4 + shuffle reduce ----------------
__global__ __launch_bounds__(256) void k_qnorm(const float* Qf, float* ws){
  const int row  = blockIdx.x*4 + (threadIdx.x >> 6);   // row = p*NQ + q
  const int lane = threadIdx.x & 63;
  const float4* q4p = (const float4*)(Qf + (size_t)row*F);
  float4 v0 = q4p[lane];
  float4 v1 = q4p[lane + 64];
  float s = v0.x*v0.x + v0.y*v0.y + v0.z*v0.z + v0.w*v0.w
          + v1.x*v1.x + v1.y*v1.y + v1.z*v1.z + v1.w*v1.w;
  for (int off = 32; off; off >>= 1) s += __shfl_down(s, off, 64);
  if (lane == 0) ws[OFF_QN + row] = s;
}

// ---------------- build M; blocked Cholesky with WAVE-SHUFFLE diag factor
//                  (zero-barrier 16x16 chol+inverse in wave 0, Dinv-matmul panel
//                  update); full blocked triangular inversion; store rowS layout ----------------
__global__ __launch_bounds__(NTF) void k_factor(float* ws){
  __shared__ float Lp[PACK];            // packed lower triangle, 115.7 KB
  __shared__ float Pn[MMAX+4][NB+1];    // SYRK panel buffer / inversion S buffer, 16.6 KB
  __shared__ float Dv[NB][NB+1];        // Dinv of current diag block, 1.1 KB
  const int blk = blockIdx.x, p = blk / C, c = blk % C;
  const int tid = threadIdx.x;
  const int* wsI = (const int*)(ws + OFF_INT);
  const int n = wsI[c];
  const int m = T + n;
  const int* idxc = wsI + C + c*MAXN;
  const float* cf = ws + OFF_CLSF + c*8;
  const float sv = cf[3], av = cf[4], sqsa = cf[5]*cf[6];
  const float* Gp  = ws + OFF_G  + (size_t)p*T*T;
  const float* g1p = ws + OFF_G1 + p*T;
  const float  ggv = ws[OFF_GG + p];
  const float* Gmp = ws + OFF_GM + (size_t)p*T*C;
  const float gmcv = ws[OFF_GMC + p*C + c];
  const float mmv  = ws[OFF_MM  + p*C + c];
  const int tot = (m*(m+1)) >> 1;

  // ---- build M packed; zero-fill tail so later uniform loops read zeros ----
  for (int e = tid; e < tot; e += NTF){
    int i = row_of(e);
    int j = e - offr(i);
    float v;
    if (i < T){
      v = sv*(Gp[i*T + j] - g1p[i] - g1p[j] + ggv);
      if (j == i) v += 1.0f;
    } else {
      int ua = idxc[i - T];
      if (j < T){
        v = sqsa*(Gp[ua*T + j] - Gmp[j*C + c] - g1p[ua] + gmcv);
      } else {
        int ub = idxc[j - T];
        v = av*(Gp[ua*T + ub] - Gmp[ua*C + c] - Gmp[ub*C + c] + mmv);
        if (j == i) v += 1.0f;
      }
    }
    Lp[e] = v;
  }
  for (int e = tot + tid; e < PACK; e += NTF) Lp[e] = 0.f;
  __syncthreads();

  // ---- blocked right-looking Cholesky ----
  for (int k0 = 0; k0 < m; k0 += NB){
    // (a) diag 16x16 Cholesky + inverse, entirely inside wave 0 (no barriers).
    //     Lane i holds row i of the block in registers. Pivots >= 1 for real rows.
    if (tid < 64){
      const int lane = tid;
      float a[NB];
      #pragma unroll
      for (int j = 0; j < NB; ++j){
        a[j] = 0.f;
        if (lane < NB && j <= lane) a[j] = Lp[offr(k0+lane) + k0 + j];
      }
      #pragma unroll
      for (int k = 0; k < NB; ++k){
        float akk = __shfl(a[k], k, 64);
        float inv = rsqrtf(akk);
        a[k] *= inv;                      // lane k gets sqrt(akk); lanes i>k get l_ik
        #pragma unroll
        for (int j = k+1; j < NB; ++j){
          float ljk = __shfl(a[k], j, 64);
          a[j] -= a[k] * ljk;
        }
      }
      // inverse: lane j computes column j; x[i]=0 for i<j emerges automatically
      float x[NB];
      #pragma unroll
      for (int i = 0; i < NB; ++i){
        float Lii = __shfl(a[i], i, 64);
        float s = 0.f;
        #pragma unroll
        for (int k2 = 0; k2 < i; ++k2){
          float Lik = __shfl(a[k2], i, 64);
          s += Lik * x[k2];
        }
        float t = ((i == lane) ? 1.f : 0.f) - s;
        x[i] = t / Lii;
      }
      if (lane < NB){
        #pragma unroll
        for (int i = 0; i < NB; ++i){
          Dv[i][lane] = (i >= lane) ? x[i] : 0.f;
          if (i >= lane) Lp[offr(k0+i) + k0 + lane] = x[i];  // Dinv into diag slots
        }
      }
    }
    __syncthreads();

    // (b) panel update: L[r][k0+j] = sum_k A[r][k0+k] * Dinv[j][k]  (fully parallel)
    for (int r = k0 + NB + tid; r < m; r += NTF){
      const int o = offr(r) + k0;
      float ar[NB];
      #pragma unroll
      for (int kk = 0; kk < NB; ++kk) ar[kk] = Lp[o + kk];
      #pragma unroll
      for (int j = 0; j < NB; ++j){
        float s = 0.f;
        #pragma unroll
        for (int kk = 0; kk <= j; ++kk) s += ar[kk] * Dv[j][kk];
        Lp[o + j] = s;
      }
    }
    __syncthreads();

    // (c) trailing SYRK update: A[i][j] -= sum_k Lpan[i][k]*Lpan[j][k]
    const int rs = m - k0 - NB;
    if (rs > 0){
      const int rsP = (rs + 3) & ~3;
      for (int e = tid; e < rsP*NB; e += NTF){
        int r = e >> 4, cl = e & 15;
        Pn[r][cl] = (r < rs) ? Lp[offr(k0+NB+r) + k0 + cl] : 0.f;
      }
      __syncthreads();
      const int nt4 = rsP >> 2;
      const int ntile = (nt4*(nt4+1)) >> 1;
      for (int e = tid; e < ntile; e += NTF){
        int ti = row_of(e);
        int tj = e - offr(ti);
        int i0 = 4*ti, j0 = 4*tj;
        float acc[4][4] = {};
        #pragma unroll 4
        for (int k = 0; k < NB; ++k){
          float a0 = Pn[i0][k], a1 = Pn[i0+1][k], a2 = Pn[i0+2][k], a3 = Pn[i0+3][k];
          float b0 = Pn[j0][k], b1 = Pn[j0+1][k], b2 = Pn[j0+2][k], b3 = Pn[j0+3][k];
          acc[0][0] += a0*b0; acc[0][1] += a0*b1; acc[0][2] += a0*b2; acc[0][3] += a0*b3;
          acc[1][0] += a1*b0; acc[1][1] += a1*b1; acc[1][2] += a1*b2; acc[1][3] += a1*b3;
          acc[2][0] += a2*b0; acc[2][1] += a2*b1; acc[2][2] += a2*b2; acc[2][3] += a2*b3;
          acc[3][0] += a3*b0; acc[3][1] += a3*b1; acc[3][2] += a3*b2; acc[3][3] += a3*b3;
        }
        #pragma unroll
        for (int u = 0; u < 4; ++u){
          int gi = k0 + NB + i0 + u;
          if (gi < m){
            int og = offr(gi);
            #pragma unroll
            for (int v2 = 0; v2 < 4; ++v2){
              int gj = k0 + NB + j0 + v2;
              if (gj <= gi) Lp[og + gj] -= acc[u][v2];
            }
          }
        }
      }
    }
    __syncthreads();
  }

  // ---- full triangular inversion: X = L^-1 in place (ascending block-rows).
  //      Diag blocks already hold Dinv; off-diag hold L. ----
  float* Sb = &Pn[0][0];   // 16 x (stride 225) = 3600 floats <= 4148 available
  for (int I = 1; I < MMAX/NB; ++I){
    const int i0 = I*NB;
    const int nct = i0 >> 2;
    const int rt = tid & 3, ct = tid >> 2;
    const int r0 = i0 + rt*4;
    const int o0 = offr(r0), o1 = offr(r0+1), o2 = offr(r0+2), o3 = offr(r0+3);
    const int j0 = ct*4;
    if (tid < 4*nct){
      float acc[4][4] = {};
      #pragma unroll
      for (int kk = 0; kk < 4; ++kk){
        const int k = j0 + kk;
        const int ok = offr(k);
        const float l0 = Lp[o0+k], l1 = Lp[o1+k], l2 = Lp[o2+k], l3 = Lp[o3+k];
        #pragma unroll
        for (int v = 0; v < 4; ++v){
          const float xv = (j0 + v <= k) ? Lp[ok + j0 + v] : 0.f;
          acc[0][v] += l0*xv; acc[1][v] += l1*xv; acc[2][v] += l2*xv; acc[3][v] += l3*xv;
        }
      }
      for (int k = j0 + 4; k < i0; ++k){
        const int ok = offr(k) + j0;
        const float l0 = Lp[o0+k], l1 = Lp[o1+k], l2 = Lp[o2+k], l3 = Lp[o3+k];
        const float x0 = Lp[ok], x1 = Lp[ok+1], x2 = Lp[ok+2], x3 = Lp[ok+3];
        acc[0][0] += l0*x0; acc[0][1] += l0*x1; acc[0][2] += l0*x2; acc[0][3] += l0*x3;
        acc[1][0] += l1*x0; acc[1][1] += l1*x1; acc[1][2] += l1*x2; acc[1][3] += l1*x3;
        acc[2][0] += l2*x0; acc[2][1] += l2*x1; acc[2][2] += l2*x2; acc[2][3] += l2*x3;
        acc[3][0] += l3*x0; acc[3][1] += l3*x1; acc[3][2] += l3*x2; acc[3][3] += l3*x3;
      }
      #pragma unroll
      for (int u = 0; u < 4; ++u)
        #pragma unroll
        for (int v = 0; v < 4; ++v)
          Sb[(rt*4+u)*225 + j0 + v] = acc[u][v];
    }
    __syncthreads();
    if (tid < 4*nct){
      float acc[4][4] = {};
      for (int s = 0; s < rt*4 + 4; ++s){
        const float d0 = (s <= rt*4    ) ? Lp[o0 + i0 + s] : 0.f;
        const float d1 = (s <= rt*4 + 1) ? Lp[o1 + i0 + s] : 0.f;
        const float d2 = (s <= rt*4 + 2) ? Lp[o2 + i0 + s] : 0.f;
        const float d3 = Lp[o3 + i0 + s];
        const float s0 = Sb[s*225 + j0], s1 = Sb[s*225 + j0 + 1];
        const float s2 = Sb[s*225 + j0 + 2], s3 = Sb[s*225 + j0 + 3];
        acc[0][0] += d0*s0; acc[0][1] += d0*s1; acc[0][2] += d0*s2; acc[0][3] += d0*s3;
        acc[1][0] += d1*s0; acc[1][1] += d1*s1; acc[1][2] += d1*s2; acc[1][3] += d1*s3;
        acc[2][0] += d2*s0; acc[2][1] += d2*s1; acc[2][2] += d2*s2; acc[2][3] += d2*s3;
        acc[3][0] += d3*s0; acc[3][1] += d3*s1; acc[3][2] += d3*s2; acc[3][3] += d3*s3;
      }
      #pragma unroll
      for (int v = 0; v < 4; ++v){
        Lp[o0 + j0 + v] = -acc[0][v];
        Lp[o1 + j0 + v] = -acc[1][v];
        Lp[o2 + j0 + v] = -acc[2][v];
        Lp[o3 + j0 + v] = -acc[3][v];
      }
    }
    __syncthreads();
  }

  // ---- store packed W = L^-1 into rowS layout; zero tail rows (>= m) ----
  float* Wg = ws + OFF_W + (size_t)blk * PACKA;
  for (int e = tid; e < tot; e += NTF){
    int i = row_of(e);
    int j = e - offr(i);
    Wg[rowS(i) + j] = Lp[e];
  }
  const int z0 = rowS(m);
  for (int e = z0 + tid; e < PACKA; e += NTF) Wg[e] = 0.f;
}

// ---------------- apply: z = W*e as tiled lower-tri GEMM; quad = ||d||^2 - ||z||^2.
//                  64-row tiles, 32-col W tiles staged to LDS (double-buffered,
//                  transposed), 4x4 register tiles, squares accumulated in regs ----------------
__global__ __launch_bounds__(256) void k_apply(float* ws){
  __shared__ float E[256][64];        // e (zero-padded to 256 rows); 64 KB
  __shared__ float Wt[2][32][64];     // W tile, [k][r] col-major; 16 KB (reused as reduce buf)
  const int p = blockIdx.z, c = blockIdx.y, q0 = blockIdx.x*64;
  const int tid = threadIdx.x;
  const int* wsI = (const int*)(ws + OFF_INT);
  const int n = wsI[c], m = T + n;
  const int* idxc = wsI + C + c*MAXN;
  const float* cf = ws + OFF_CLSF + c*8;
  const float sqs = cf[5], sqa = cf[6];
  const float gmcv = ws[OFF_GMC + p*C + c];
  const float mmv  = ws[OFF_MM  + p*C + c];
  const float* Gmp = ws + OFF_GM + (size_t)p*T*C;
  const float* SQp = ws + OFF_SQ + (size_t)p*T*NQ;
  const float* gqp = ws + OFF_GQ + p*NQ + q0;
  const float* qnp = ws + OFF_QN + p*NQ + q0;
  const float* mqp = ws + OFF_MQ + ((size_t)(p*C + c))*NQ + q0;
  const float* Wg  = ws + OFF_W + (size_t)(p*C + c)*PACKA;

  // ---- build E rows 0..255 (zero pad >= m) ----
  for (int lin = tid; lin < 256*64; lin += 256){
    int j = lin >> 6, ql = lin & 63;
    float v = 0.f;
    if (j < T){
      v = sqs*(Gmp[j*C + c] - SQp[j*NQ + q0 + ql] - gmcv + gqp[ql]);
    } else if (j < m){
      int u = idxc[j - T];
      v = sqa*(Gmp[u*C + c] - SQp[u*NQ + q0 + ql] - mmv + mqp[ql]);
    }
    E[j][ql] = v;
  }
  __syncthreads();

  const int rg4 = (tid >> 4) * 4;     // 4 rows within row-tile
  const int cg4 = (tid & 15) * 4;     // 4 query columns
  const int sr  = tid >> 2;           // staging: row within tile (0..63)
  const int sk  = (tid & 3) * 8;      // staging: 8 cols starting here
  float ss0 = 0.f, ss1 = 0.f, ss2 = 0.f, ss3 = 0.f;

  for (int R = 0; R < 4; ++R){
    const int i0 = R*64;
    const int nct = 2*R + 2;
    // stage tile ct=0 into buf 0
    {
      const int i = i0 + sr, j0s = sk;
      float v[8] = {};
      if (i < MMAX && j0s <= i){
        const float* wr = Wg + rowS(i) + j0s;
        if (j0s + 7 <= i){
          float4 a = *(const float4*)wr, b = *(const float4*)(wr+4);
          v[0]=a.x; v[1]=a.y; v[2]=a.z; v[3]=a.w; v[4]=b.x; v[5]=b.y; v[6]=b.z; v[7]=b.w;
        } else {
          #pragma unroll
          for (int u = 0; u < 8; ++u) if (j0s + u <= i) v[u] = wr[u];
        }
      }
      #pragma unroll
      for (int u = 0; u < 8; ++u) Wt[0][sk+u][sr] = v[u];
    }
    __syncthreads();

    float acc[4][4] = {};
    for (int ct = 0; ct < nct; ++ct){
      const int buf = ct & 1;
      if (ct + 1 < nct){   // prefetch next tile into other buffer
        const int i = i0 + sr, j0s = (ct+1)*32 + sk;
        float v[8] = {};
        if (i < MMAX && j0s <= i){
          const float* wr = Wg + rowS(i) + j0s;
          if (j0s + 7 <= i){
            float4 a = *(const float4*)wr, b = *(const float4*)(wr+4);
            v[0]=a.x; v[1]=a.y; v[2]=a.z; v[3]=a.w; v[4]=b.x; v[5]=b.y; v[6]=b.z; v[7]=b.w;
          } else {
            #pragma unroll
            for (int u = 0; u < 8; ++u) if (j0s + u <= i) v[u] = wr[u];
          }
        }
        #pragma unroll
        for (int u = 0; u < 8; ++u) Wt[buf^1][sk+u][sr] = v[u];
      }
      const int j0 = ct*32;
      #pragma unroll 4
      for (int k = 0; k < 32; ++k){
        const float4 w = *(const float4*)&Wt[buf][k][rg4];
        const float4 e = *(const float4*)&E[j0+k][cg4];
        acc[0][0] += w.x*e.x; acc[0][1] += w.x*e.y; acc[0][2] += w.x*e.z; acc[0][3] += w.x*e.w;
        acc[1][0] += w.y*e.x; acc[1][1] += w.y*e.y; acc[1][2] += w.y*e.z; acc[1][3] += w.y*e.w;
        acc[2][0] += w.z*e.x; acc[2][1] += w.z*e.y; acc[2][2] += w.z*e.z; acc[2][3] += w.z*e.w;
        acc[3][0] += w.w*e.x; acc[3][1] += w.w*e.y; acc[3][2] += w.w*e.z; acc[3][3] += w.w*e.w;
      }
      __syncthreads();
    }
    ss0 += acc[0][0]*acc[0][0] + acc[1][0]*acc[1][0] + acc[2][0]*acc[2][0] + acc[3][0]*acc[3][0];
    ss1 += acc[0][1]*acc[0][1] + acc[1][1]*acc[1][1] + acc[2][1]*acc[2][1] + acc[3][1]*acc[3][1];
    ss2 += acc[0][2]*acc[0][2] + acc[1][2]*acc[1][2] + acc[2][2]*acc[2][2] + acc[3][2]*acc[3][2];
    ss3 += acc[0][3]*acc[0][3] + acc[1][3]*acc[1][3] + acc[2][3]*acc[2][3] + acc[3][3]*acc[3][3];
  }

  // ---- reduce over the 16 row-groups per query (reuse Wt as buffer) ----
  float* Rb = &Wt[0][0][0];
  const int rg = tid >> 4;
  Rb[rg*64 + cg4 + 0] = ss0;
  Rb[rg*64 + cg4 + 1] = ss1;
  Rb[rg*64 + cg4 + 2] = ss2;
  Rb[rg*64 + cg4 + 3] = ss3;
  __syncthreads();
  if (tid < 64){
    float tt = 0.f;
    #pragma unroll
    for (int g = 0; g < 16; ++g) tt += Rb[g*64 + tid];
    float quad = mmv - 2.f*mqp[tid] + qnp[tid] - tt;
    ws[OFF_QUAD + ((size_t)p*NQ + q0 + tid)*C + c] = quad;
  }
}

// ---------------- logits: mean over p ----------------
__global__ void k_logits(const float* ws, float* out){
  int lin = blockIdx.x*256 + threadIdx.x;
  if (lin < QL){
    float s = 0.f;
    for (int p = 0; p < P; ++p) s += ws[OFF_QUAD + (size_t)p*NQ*C + lin];
    out[lin] = -s * (1.0f/P);
  }
}

extern "C" void kernel_launch(void* const* d_in, const int* in_sizes, int n_in,
                              void* d_out, int out_size, void* d_ws, size_t ws_size,
                              hipStream_t stream){
  const float* X   = (const float*)d_in[0];
  const int*   lab = (const int*)d_in[1];
  const float* Qf  = (const float*)d_in[2];
  float* out = (float*)d_out;
  float* ws  = (float*)d_ws;

  k_setup <<<1, 64, 0, stream>>>(lab, ws);
  k_gram  <<<dim3(7,7,P),  dim3(16,16), 0, stream>>>(X, ws);
  k_pstats<<<P, 256, 0, stream>>>(ws);
  k_means <<<P*C, 256, 0, stream>>>(X, ws, out);
  k_sq    <<<dim3(7,16,P), dim3(16,16), 0, stream>>>(X, Qf, ws);
  k_qstats<<<dim3(4,P), 256, 0, stream>>>(ws);
  k_qnorm <<<(P*NQ)/4, 256, 0, stream>>>(Qf, ws);
  k_factor<<<P*C, NTF, 0, stream>>>(ws);
  k_apply <<<dim3(16,C,P), 256, 0, stream>>>(ws);
  k_logits<<<QL/256, 256, 0, stream>>>(ws, out);
}

// Round 7
// 901.767 us; speedup vs baseline: 2.1172x; 1.0513x over previous
//
#include <hip/hip_runtime.h>

// Problem constants (fixed by the reference)
#define P 8
#define T 200
#define C 20
#define F 512
#define NQ 1024
#define MAXN 40                    // max samples per class we support (true ~10±4)
#define MMAX (T + MAXN)            // 240
#define PACK ((MMAX*(MMAX+1))/2)   // 28920 packed lower-tri floats
#define PACKA 29280                // row-padded-to-4 packed layout = rowS(MMAX)
#define QL (NQ*C)                  // 20480 logits
#define NB 16                      // Cholesky panel width
#define NTF 1024                   // k_factor block size (16 waves)

// Workspace layout (float offsets)
enum : int {
  OFF_G    = 0,                       // P*T*T      = 320000
  OFF_SQ   = OFF_G   + P*T*T,         // P*T*NQ     = 1638400
  OFF_G1   = OFF_SQ  + P*T*NQ,        // P*T
  OFF_GG   = OFF_G1  + P*T,           // P
  OFF_GM   = OFF_GG  + P,             // P*T*C
  OFF_GMC  = OFF_GM  + P*T*C,         // P*C
  OFF_MM   = OFF_GMC + P*C,           // P*C
  OFF_GQ   = OFF_MM  + P*C,           // P*NQ
  OFF_QN   = OFF_GQ  + P*NQ,          // P*NQ
  OFF_MQ   = OFF_QN  + P*NQ,          // P*C*NQ
  OFF_W    = OFF_MQ  + P*C*NQ,        // P*C*PACKA : packed FULL INVERSE W=L^-1, rows>=m zeroed
  OFF_QUAD = OFF_W   + P*C*PACKA,     // P*NQ*C
  OFF_CLSF = OFF_QUAD+ P*NQ*C,        // C*8 scalars
  OFF_INT  = OFF_CLSF+ C*8            // int region: counts[C], idx[C*MAXN]
};

__device__ __forceinline__ int offr(int i){ return (i*(i+1))>>1; }

// 4-aligned row-padded packed layout: row i at rowS(i), length padded to mult of 4.
__device__ __forceinline__ int rowS(int i){
  int a = i >> 2, r = i & 3;
  return 8*a*(a+1) + 4*r*(a+1);
}

// flat packed index e -> row i (offr layout, used for tile triangles)
__device__ __forceinline__ int row_of(int e){
  int i = (int)((sqrtf(8.f*(float)e + 1.f) - 1.f) * 0.5f);
  while (offr(i+1) <= e) ++i;
  while (offr(i) > e) --i;
  return i;
}

// flat index e -> row i in rowS layout
__device__ __forceinline__ int row_ofS(int e){
  int i = (int)sqrtf(2.f*(float)e);
  if (i > MMAX-1) i = MMAX-1;
  while (i < MMAX-1 && rowS(i+1) <= e) ++i;
  while (i > 0 && rowS(i) > e) --i;
  return i;
}

// ---------------- setup: counts, per-class index lists, scalars ----------------
__global__ void k_setup(const int* lab, float* ws){
  int c = threadIdx.x;
  if (c >= C) return;
  int* wsI = (int*)(ws + OFF_INT);
  int n = 0;
  for (int t = 0; t < T; ++t){
    if (lab[t] == c){ if (n < MAXN) wsI[C + c*MAXN + n] = t; ++n; }
  }
  if (n > MAXN) n = MAXN;
  wsI[c] = n;
  float nf    = (float)n;
  float nsafe = fmaxf(nf, 1.0f);
  float dn    = fmaxf(nf - 1.0f, 1.0f);
  float lam   = nsafe / (nsafe + 1.0f);
  float sv    = (1.0f - lam) / (float)(T - 1);
  float av    = lam / dn;
  float* cf = ws + OFF_CLSF + c*8;
  cf[0] = nsafe; cf[1] = dn; cf[2] = lam; cf[3] = sv; cf[4] = av;
  cf[5] = sqrtf(sv); cf[6] = sqrtf(av); cf[7] = 0.0f;
}

// ---------------- G = X X^T per p (200x200) ----------------
__global__ __launch_bounds__(256) void k_gram(const float* X, float* ws){
  __shared__ float Xi[32][33];
  __shared__ float Xj[32][33];
  const int p = blockIdx.z, i0 = blockIdx.y*32, j0 = blockIdx.x*32;
  const int tx = threadIdx.x, ty = threadIdx.y;
  const int tid = ty*16 + tx;
  const float* Xp = X + (size_t)p*T*F;
  float acc[2][2] = {{0.f,0.f},{0.f,0.f}};
  for (int kb = 0; kb < F; kb += 32){
    for (int e = tid; e < 32*32; e += 256){
      int r = e >> 5, kk = e & 31;
      Xi[r][kk] = (i0+r < T) ? Xp[(i0+r)*F + kb+kk] : 0.f;
      Xj[r][kk] = (j0+r < T) ? Xp[(j0+r)*F + kb+kk] : 0.f;
    }
    __syncthreads();
    for (int kk = 0; kk < 32; ++kk){
      float a0 = Xi[2*ty][kk],   a1 = Xi[2*ty+1][kk];
      float b0 = Xj[2*tx][kk],   b1 = Xj[2*tx+1][kk];
      acc[0][0] += a0*b0; acc[0][1] += a0*b1;
      acc[1][0] += a1*b0; acc[1][1] += a1*b1;
    }
    __syncthreads();
  }
  float* Gp = ws + OFF_G + (size_t)p*T*T;
  for (int a = 0; a < 2; ++a)
    for (int b = 0; b < 2; ++b){
      int i = i0 + 2*ty + a, j = j0 + 2*tx + b;
      if (i < T && j < T) Gp[i*T + j] = acc[a][b];
    }
}

// ---------------- per-p stats part A: g1 rows + Gm (coalesced, 200 blocks) ----------------
__global__ __launch_bounds__(256) void k_pstats_a(float* ws){
  const int p = blockIdx.y, bx = blockIdx.x;      // bx in [0,25)
  const int w = threadIdx.x >> 6, lane = threadIdx.x & 63;
  const int* wsI = (const int*)(ws + OFF_INT);
  const float* Gp = ws + OFF_G + (size_t)p*T*T;
  float* g1 = ws + OFF_G1 + p*T;
  float* Gm = ws + OFF_GM + (size_t)p*T*C;
  for (int rr = 0; rr < 2; ++rr){
    const int t = bx*8 + w*2 + rr;                // 25*8 = 200 rows exactly
    float s = 0.f;
    for (int u = lane; u < T; u += 64) s += Gp[t*T + u];
    for (int off = 32; off; off >>= 1) s += __shfl_down(s, off, 64);
    if (lane == 0) g1[t] = s * (1.0f/T);
    if (lane < C){
      int c = lane, nn = wsI[c];
      const int* idxc = wsI + C + c*MAXN;
      float sc = 0.f;
      for (int j = 0; j < nn; ++j) sc += Gp[t*T + idxc[j]];
      Gm[t*C + c] = sc / ws[OFF_CLSF + c*8];
    }
  }
}

// ---------------- per-p stats part B: gg, gmc, mm ----------------
__global__ __launch_bounds__(256) void k_pstats_b(float* ws){
  __shared__ float red[64];
  const int p = blockIdx.x, tid = threadIdx.x;
  const int* wsI = (const int*)(ws + OFF_INT);
  const float* g1 = ws + OFF_G1 + p*T;
  const float* Gm = ws + OFF_GM + (size_t)p*T*C;
  if (tid < 64){
    float s = 0.f;
    for (int t = tid; t < T; t += 64) s += g1[t];
    red[tid] = s;
  }
  __syncthreads();
  if (tid == 0){
    float s = 0.f;
    for (int k = 0; k < 64; ++k) s += red[k];
    ws[OFF_GG + p] = s * (1.0f/T);
  }
  if (tid < C){
    int c = tid, nn = wsI[c];
    const int* idxc = wsI + C + c*MAXN;
    float s = 0.f;
    for (int t = 0; t < T; ++t) s += Gm[t*C + c];
    ws[OFF_GMC + p*C + c] = s * (1.0f/T);
    float s2 = 0.f;
    for (int j = 0; j < nn; ++j) s2 += Gm[idxc[j]*C + c];
    ws[OFF_MM + p*C + c] = s2 / ws[OFF_CLSF + c*8];
  }
}

// ---------------- class means -> output part 2 ----------------
__global__ __launch_bounds__(256) void k_means(const float* X, const float* ws, float* out){
  const int blk = blockIdx.x, p = blk / C, c = blk % C;
  const int* wsI = (const int*)(ws + OFF_INT);
  const int n = wsI[c];
  const int* idxc = wsI + C + c*MAXN;
  const float nf = ws[OFF_CLSF + c*8];
  const float* Xp = X + (size_t)p*T*F;
  float* o = out + QL + (size_t)(p*C + c)*F;
  for (int f = threadIdx.x; f < F; f += 256){
    float s = 0.f;
    for (int j = 0; j < n; ++j) s += Xp[idxc[j]*F + f];
    o[f] = s / nf;
  }
}

// ---------------- SQ = X Q^T per p (200x1024) ----------------
__global__ __launch_bounds__(256) void k_sq(const float* X, const float* Qf, float* ws){
  __shared__ float Xt[32][33];
  __shared__ float Qt[64][33];
  const int p = blockIdx.z, t0 = blockIdx.x*32, q0 = blockIdx.y*64;
  const int tx = threadIdx.x, ty = threadIdx.y;
  const int tid = ty*16 + tx;
  const float* Xp = X  + (size_t)p*T*F;
  const float* Qp = Qf + (size_t)p*NQ*F;
  float acc[2][4] = {};
  for (int kb = 0; kb < F; kb += 32){
    for (int e = tid; e < 32*32; e += 256){
      int r = e >> 5, kk = e & 31;
      Xt[r][kk] = (t0+r < T) ? Xp[(t0+r)*F + kb+kk] : 0.f;
    }
    for (int e = tid; e < 64*32; e += 256){
      int r = e >> 5, kk = e & 31;
      Qt[r][kk] = Qp[(q0+r)*F + kb+kk];
    }
    __syncthreads();
    for (int kk = 0; kk < 32; ++kk){
      float a0 = Xt[2*ty][kk], a1 = Xt[2*ty+1][kk];
      float b0 = Qt[4*tx][kk], b1 = Qt[4*tx+1][kk], b2 = Qt[4*tx+2][kk], b3 = Qt[4*tx+3][kk];
      acc[0][0] += a0*b0; acc[0][1] += a0*b1; acc[0][2] += a0*b2; acc[0][3] += a0*b3;
      acc[1][0] += a1*b0; acc[1][1] += a1*b1; acc[1][2] += a1*b2; acc[1][3] += a1*b3;
    }
    __syncthreads();
  }
  float* SQp = ws + OFF_SQ + (size_t)p*T*NQ;
  for (int a = 0; a < 2; ++a){
    int t = t0 + 2*ty + a;
    if (t < T)
      for (int b = 0; b < 4; ++b)
        SQp[t*NQ + q0 + 4*tx + b] = acc[a][b];
  }
}

// ---------------- per-q stats: gq, mq (chunked, 128 blocks) ----------------
__global__ __launch_bounds__(256) void k_qstats(float* ws){
  __shared__ float red[4][64];
  const int p = blockIdx.y;
  const int qb = blockIdx.x*64;                   // gridDim.x = 16
  const int chunk = threadIdx.x >> 6, lane = threadIdx.x & 63;
  const int q = qb + lane;
  const int* wsI = (const int*)(ws + OFF_INT);
  const float* SQp = ws + OFF_SQ + (size_t)p*T*NQ;
  float s = 0.f;
  for (int t = chunk*50; t < chunk*50 + 50; ++t) s += SQp[t*NQ + q];
  red[chunk][lane] = s;
  __syncthreads();
  if (chunk == 0){
    float tot = red[0][lane] + red[1][lane] + red[2][lane] + red[3][lane];
    ws[OFF_GQ + p*NQ + q] = tot * (1.0f/T);
  }
  for (int c = chunk; c < C; c += 4){
    int nn = wsI[c];
    const int* idxc = wsI + C + c*MAXN;
    float sc = 0.f;
    for (int j = 0; j < nn; ++j) sc += SQp[idxc[j]*NQ + q];
    ws[OFF_MQ + ((size_t)(p*C + c))*NQ + q] = sc / ws[OFF_CLSF + c*8];
  }
}

// ---------------- qn = ||q||^2, one wave per row ----------------
__global__ __launch_bounds__(256) void k_qnorm(const float* Qf, float* ws){
  const int row  = blockIdx.x*4 + (threadIdx.x >> 6);
  const int lane = threadIdx.x & 63;
  const float4* q4p = (const float4*)(Qf + (size_t)row*F);
  float4 v0 = q4p[lane];
  float4 v1 = q4p[lane + 64];
  float s = v0.x*v0.x + v0.y*v0.y + v0.z*v0.z + v0.w*v0.w
          + v1.x*v1.x + v1.y*v1.y + v1.z*v1.z + v1.w*v1.w;
  for (int off = 32; off; off >>= 1) s += __shfl_down(s, off, 64);
  if (lane == 0) ws[OFF_QN + row] = s;
}

// ---------------- build M; blocked Cholesky (wave-shuffle diag); full blocked
//                  triangular inversion. LDS triangle in rowS layout: every row
//                  16B-aligned, pads zero -> all hot loops are b128, no masks. ----------------
__global__ __launch_bounds__(NTF) void k_factor(float* ws){
  __shared__ float Lp[PACKA];           // 117120 B, rowS-packed lower triangle
  __shared__ float Sb[16*228];          // 14592 B inversion stage buffer (stride 228: 16B-aligned rows)
  __shared__ float Dv[NB][NB+1];        // 1088 B Dinv of current diag block
  const int blk = blockIdx.x, p = blk / C, c = blk % C;
  const int tid = threadIdx.x;
  const int* wsI = (const int*)(ws + OFF_INT);
  const int n = wsI[c];
  const int m = T + n;
  const int* idxc = wsI + C + c*MAXN;
  const float* cf = ws + OFF_CLSF + c*8;
  const float sv = cf[3], av = cf[4], sqsa = cf[5]*cf[6];
  const float* Gp  = ws + OFF_G  + (size_t)p*T*T;
  const float* g1p = ws + OFF_G1 + p*T;
  const float  ggv = ws[OFF_GG + p];
  const float* Gmp = ws + OFF_GM + (size_t)p*T*C;
  const float gmcv = ws[OFF_GMC + p*C + c];
  const float mmv  = ws[OFF_MM  + p*C + c];

  // ---- build M in rowS layout; pads and rows >= m zeroed ----
  for (int e = tid; e < PACKA; e += NTF){
    int i = row_ofS(e);
    int j = e - rowS(i);
    float v = 0.f;
    if (i < m && j <= i){
      if (i < T){
        v = sv*(Gp[i*T + j] - g1p[i] - g1p[j] + ggv);
        if (j == i) v += 1.0f;
      } else {
        int ua = idxc[i - T];
        if (j < T){
          v = sqsa*(Gp[ua*T + j] - Gmp[j*C + c] - g1p[ua] + gmcv);
        } else {
          int ub = idxc[j - T];
          v = av*(Gp[ua*T + ub] - Gmp[ua*C + c] - Gmp[ub*C + c] + mmv);
          if (j == i) v += 1.0f;
        }
      }
    }
    Lp[e] = v;
  }
  __syncthreads();

  // ---- blocked right-looking Cholesky ----
  for (int k0 = 0; k0 < m; k0 += NB){
    // (a) diag 16x16 Cholesky + inverse inside wave 0 (no barriers)
    if (tid < 64){
      const int lane = tid;
      float a[NB];
      #pragma unroll
      for (int j = 0; j < NB; ++j){
        a[j] = 0.f;
        if (lane < NB && j <= lane) a[j] = Lp[rowS(k0+lane) + k0 + j];
      }
      #pragma unroll
      for (int k = 0; k < NB; ++k){
        float akk = __shfl(a[k], k, 64);
        float inv = rsqrtf(akk);
        a[k] *= inv;
        #pragma unroll
        for (int j = k+1; j < NB; ++j){
          float ljk = __shfl(a[k], j, 64);
          a[j] -= a[k] * ljk;
        }
      }
      float x[NB];
      #pragma unroll
      for (int i = 0; i < NB; ++i){
        float Lii = __shfl(a[i], i, 64);
        float sxx = 0.f;
        #pragma unroll
        for (int k2 = 0; k2 < i; ++k2){
          float Lik = __shfl(a[k2], i, 64);
          sxx += Lik * x[k2];
        }
        float tt = ((i == lane) ? 1.f : 0.f) - sxx;
        x[i] = tt / Lii;
      }
      if (lane < NB){
        #pragma unroll
        for (int i = 0; i < NB; ++i){
          Dv[i][lane] = (i >= lane) ? x[i] : 0.f;
          if (i >= lane) Lp[rowS(k0+i) + k0 + lane] = x[i];
        }
      }
    }
    __syncthreads();

    // (b) panel update: L[r][k0+j] = sum_{kk<=j} A[r][k0+kk] * Dinv[j][kk]
    for (int r = k0 + NB + tid; r < m; r += NTF){
      const int o = rowS(r) + k0;
      float4 A0 = *(const float4*)&Lp[o];
      float4 A1 = *(const float4*)&Lp[o+4];
      float4 A2 = *(const float4*)&Lp[o+8];
      float4 A3 = *(const float4*)&Lp[o+12];
      float ar[NB] = {A0.x,A0.y,A0.z,A0.w, A1.x,A1.y,A1.z,A1.w,
                      A2.x,A2.y,A2.z,A2.w, A3.x,A3.y,A3.z,A3.w};
      float sr[NB];
      #pragma unroll
      for (int j = 0; j < NB; ++j){
        float s = 0.f;
        #pragma unroll
        for (int kk = 0; kk <= j; ++kk) s += ar[kk] * Dv[j][kk];
        sr[j] = s;
      }
      *(float4*)&Lp[o]    = make_float4(sr[0], sr[1], sr[2], sr[3]);
      *(float4*)&Lp[o+4]  = make_float4(sr[4], sr[5], sr[6], sr[7]);
      *(float4*)&Lp[o+8]  = make_float4(sr[8], sr[9], sr[10], sr[11]);
      *(float4*)&Lp[o+12] = make_float4(sr[12], sr[13], sr[14], sr[15]);
    }
    __syncthreads();

    // (c) trailing SYRK directly from Lp (b128 reads; rows >= m are zero)
    const int rs = m - k0 - NB;
    if (rs > 0){
      const int base = k0 + NB;
      const int nt4 = (rs + 3) >> 2;
      const int ntile = (nt4*(nt4+1)) >> 1;
      for (int e2 = tid; e2 < ntile; e2 += NTF){
        const int ti = row_of(e2);
        const int tj = e2 - offr(ti);
        const int gi0 = base + 4*ti, gj0 = base + 4*tj;
        const float* pa0 = &Lp[rowS(gi0)   + k0];
        const float* pa1 = &Lp[rowS(gi0+1) + k0];
        const float* pa2 = &Lp[rowS(gi0+2) + k0];
        const float* pa3 = &Lp[rowS(gi0+3) + k0];
        const float* pb0 = &Lp[rowS(gj0)   + k0];
        const float* pb1 = &Lp[rowS(gj0+1) + k0];
        const float* pb2 = &Lp[rowS(gj0+2) + k0];
        const float* pb3 = &Lp[rowS(gj0+3) + k0];
        float acc[4][4] = {};
        #pragma unroll
        for (int kk = 0; kk < NB; kk += 4){
          float4 a0 = *(const float4*)(pa0+kk);
          float4 a1 = *(const float4*)(pa1+kk);
          float4 a2 = *(const float4*)(pa2+kk);
          float4 a3 = *(const float4*)(pa3+kk);
          float4 b0 = *(const float4*)(pb0+kk);
          float4 b1 = *(const float4*)(pb1+kk);
          float4 b2 = *(const float4*)(pb2+kk);
          float4 b3 = *(const float4*)(pb3+kk);
          acc[0][0] += a0.x*b0.x + a0.y*b0.y + a0.z*b0.z + a0.w*b0.w;
          acc[0][1] += a0.x*b1.x + a0.y*b1.y + a0.z*b1.z + a0.w*b1.w;
          acc[0][2] += a0.x*b2.x + a0.y*b2.y + a0.z*b2.z + a0.w*b2.w;
          acc[0][3] += a0.x*b3.x + a0.y*b3.y + a0.z*b3.z + a0.w*b3.w;
          acc[1][0] += a1.x*b0.x + a1.y*b0.y + a1.z*b0.z + a1.w*b0.w;
          acc[1][1] += a1.x*b1.x + a1.y*b1.y + a1.z*b1.z + a1.w*b1.w;
          acc[1][2] += a1.x*b2.x + a1.y*b2.y + a1.z*b2.z + a1.w*b2.w;
          acc[1][3] += a1.x*b3.x + a1.y*b3.y + a1.z*b3.z + a1.w*b3.w;
          acc[2][0] += a2.x*b0.x + a2.y*b0.y + a2.z*b0.z + a2.w*b0.w;
          acc[2][1] += a2.x*b1.x + a2.y*b1.y + a2.z*b1.z + a2.w*b1.w;
          acc[2][2] += a2.x*b2.x + a2.y*b2.y + a2.z*b2.z + a2.w*b2.w;
          acc[2][3] += a2.x*b3.x + a2.y*b3.y + a2.z*b3.z + a2.w*b3.w;
          acc[3][0] += a3.x*b0.x + a3.y*b0.y + a3.z*b0.z + a3.w*b0.w;
          acc[3][1] += a3.x*b1.x + a3.y*b1.y + a3.z*b1.z + a3.w*b1.w;
          acc[3][2] += a3.x*b2.x + a3.y*b2.y + a3.z*b2.z + a3.w*b2.w;
          acc[3][3] += a3.x*b3.x + a3.y*b3.y + a3.z*b3.z + a3.w*b3.w;
        }
        #pragma unroll
        for (int u = 0; u < 4; ++u){
          const int gi = gi0 + u;
          if (gi < m){
            const int og = rowS(gi);
            if (gj0 + 3 <= gi){
              float4 t = *(float4*)&Lp[og + gj0];
              t.x -= acc[u][0]; t.y -= acc[u][1]; t.z -= acc[u][2]; t.w -= acc[u][3];
              *(float4*)&Lp[og + gj0] = t;
            } else {
              #pragma unroll
              for (int v = 0; v < 4; ++v){
                const int gj = gj0 + v;
                if (gj <= gi) Lp[og + gj] -= acc[u][v];
              }
            }
          }
        }
      }
    }
    __syncthreads();
  }

  // ---- full triangular inversion in place (ascending block-rows, all b128) ----
  for (int I = 1; I < MMAX/NB; ++I){
    const int i0 = I*NB;
    const int nct = i0 >> 2;
    const int rt = tid & 3, ct = tid >> 2;
    const int rt4 = rt*4;
    const int j0 = ct*4;
    int o0 = 0, o1 = 0, o2 = 0, o3 = 0;
    if (tid < 4*nct){
      const int r0 = i0 + rt4;
      o0 = rowS(r0); o1 = rowS(r0+1); o2 = rowS(r0+2); o3 = rowS(r0+3);
      float acc[4][4] = {};
      for (int k = j0; k < i0; k += 4){
        float4 l0 = *(const float4*)&Lp[o0+k];
        float4 l1 = *(const float4*)&Lp[o1+k];
        float4 l2 = *(const float4*)&Lp[o2+k];
        float4 l3 = *(const float4*)&Lp[o3+k];
        float4 x0 = *(const float4*)&Lp[rowS(k)  +j0];
        float4 x1 = *(const float4*)&Lp[rowS(k+1)+j0];
        float4 x2 = *(const float4*)&Lp[rowS(k+2)+j0];
        float4 x3 = *(const float4*)&Lp[rowS(k+3)+j0];
        acc[0][0] += l0.x*x0.x + l0.y*x1.x + l0.z*x2.x + l0.w*x3.x;
        acc[0][1] += l0.x*x0.y + l0.y*x1.y + l0.z*x2.y + l0.w*x3.y;
        acc[0][2] += l0.x*x0.z + l0.y*x1.z + l0.z*x2.z + l0.w*x3.z;
        acc[0][3] += l0.x*x0.w + l0.y*x1.w + l0.z*x2.w + l0.w*x3.w;
        acc[1][0] += l1.x*x0.x + l1.y*x1.x + l1.z*x2.x + l1.w*x3.x;
        acc[1][1] += l1.x*x0.y + l1.y*x1.y + l1.z*x2.y + l1.w*x3.y;
        acc[1][2] += l1.x*x0.z + l1.y*x1.z + l1.z*x2.z + l1.w*x3.z;
        acc[1][3] += l1.x*x0.w + l1.y*x1.w + l1.z*x2.w + l1.w*x3.w;
        acc[2][0] += l2.x*x0.x + l2.y*x1.x + l2.z*x2.x + l2.w*x3.x;
        acc[2][1] += l2.x*x0.y + l2.y*x1.y + l2.z*x2.y + l2.w*x3.y;
        acc[2][2] += l2.x*x0.z + l2.y*x1.z + l2.z*x2.z + l2.w*x3.z;
        acc[2][3] += l2.x*x0.w + l2.y*x1.w + l2.z*x2.w + l2.w*x3.w;
        acc[3][0] += l3.x*x0.x + l3.y*x1.x + l3.z*x2.x + l3.w*x3.x;
        acc[3][1] += l3.x*x0.y + l3.y*x1.y + l3.z*x2.y + l3.w*x3.y;
        acc[3][2] += l3.x*x0.z + l3.y*x1.z + l3.z*x2.z + l3.w*x3.z;
        acc[3][3] += l3.x*x0.w + l3.y*x1.w + l3.z*x2.w + l3.w*x3.w;
      }
      *(float4*)&Sb[(rt4  )*228 + j0] = make_float4(acc[0][0], acc[0][1], acc[0][2], acc[0][3]);
      *(float4*)&Sb[(rt4+1)*228 + j0] = make_float4(acc[1][0], acc[1][1], acc[1][2], acc[1][3]);
      *(float4*)&Sb[(rt4+2)*228 + j0] = make_float4(acc[2][0], acc[2][1], acc[2][2], acc[2][3]);
      *(float4*)&Sb[(rt4+3)*228 + j0] = make_float4(acc[3][0], acc[3][1], acc[3][2], acc[3][3]);
    }
    __syncthreads();
    if (tid < 4*nct){
      float acc[4][4] = {};
      for (int s = 0; s < rt4 + 4; ++s){
        const float d0 = Lp[o0 + i0 + s];   // pads beyond row give zero
        const float d1 = Lp[o1 + i0 + s];
        const float d2 = Lp[o2 + i0 + s];
        const float d3 = Lp[o3 + i0 + s];
        const float4 sv4 = *(const float4*)&Sb[s*228 + j0];
        acc[0][0] += d0*sv4.x; acc[0][1] += d0*sv4.y; acc[0][2] += d0*sv4.z; acc[0][3] += d0*sv4.w;
        acc[1][0] += d1*sv4.x; acc[1][1] += d1*sv4.y; acc[1][2] += d1*sv4.z; acc[1][3] += d1*sv4.w;
        acc[2][0] += d2*sv4.x; acc[2][1] += d2*sv4.y; acc[2][2] += d2*sv4.z; acc[2][3] += d2*sv4.w;
        acc[3][0] += d3*sv4.x; acc[3][1] += d3*sv4.y; acc[3][2] += d3*sv4.z; acc[3][3] += d3*sv4.w;
      }
      *(float4*)&Lp[o0 + j0] = make_float4(-acc[0][0], -acc[0][1], -acc[0][2], -acc[0][3]);
      *(float4*)&Lp[o1 + j0] = make_float4(-acc[1][0], -acc[1][1], -acc[1][2], -acc[1][3]);
      *(float4*)&Lp[o2 + j0] = make_float4(-acc[2][0], -acc[2][1], -acc[2][2], -acc[2][3]);
      *(float4*)&Lp[o3 + j0] = make_float4(-acc[3][0], -acc[3][1], -acc[3][2], -acc[3][3]);
    }
    __syncthreads();
  }

  // ---- store W = L^-1 (straight float4 copy; rows >= m forced to zero) ----
  float4* Wg4 = (float4*)(ws + OFF_W + (size_t)blk * PACKA);
  const float4* Lp4 = (const float4*)Lp;
  const int z4 = rowS(m) >> 2;
  for (int e4 = tid; e4 < PACKA/4; e4 += NTF){
    float4 v = Lp4[e4];
    if (e4 >= z4) v = make_float4(0.f, 0.f, 0.f, 0.f);
    Wg4[e4] = v;
  }
}

// ---------------- apply: z = W*e as tiled lower-tri GEMM; quad = ||d||^2 - ||z||^2 ----------------
__global__ __launch_bounds__(256) void k_apply(float* ws){
  __shared__ float E[256][64];        // e (zero-padded to 256 rows); 64 KB
  __shared__ float Wt[2][32][64];     // W tile, [k][r] col-major; 16 KB
  const int p = blockIdx.z, c = blockIdx.y, q0 = blockIdx.x*64;
  const int tid = threadIdx.x;
  const int* wsI = (const int*)(ws + OFF_INT);
  const int n = wsI[c], m = T + n;
  const int* idxc = wsI + C + c*MAXN;
  const float* cf = ws + OFF_CLSF + c*8;
  const float sqs = cf[5], sqa = cf[6];
  const float gmcv = ws[OFF_GMC + p*C + c];
  const float mmv  = ws[OFF_MM  + p*C + c];
  const float* Gmp = ws + OFF_GM + (size_t)p*T*C;
  const float* SQp = ws + OFF_SQ + (size_t)p*T*NQ;
  const float* gqp = ws + OFF_GQ + p*NQ + q0;
  const float* qnp = ws + OFF_QN + p*NQ + q0;
  const float* mqp = ws + OFF_MQ + ((size_t)(p*C + c))*NQ + q0;
  const float* Wg  = ws + OFF_W + (size_t)(p*C + c)*PACKA;

  for (int lin = tid; lin < 256*64; lin += 256){
    int j = lin >> 6, ql = lin & 63;
    float v = 0.f;
    if (j < T){
      v = sqs*(Gmp[j*C + c] - SQp[j*NQ + q0 + ql] - gmcv + gqp[ql]);
    } else if (j < m){
      int u = idxc[j - T];
      v = sqa*(Gmp[u*C + c] - SQp[u*NQ + q0 + ql] - mmv + mqp[ql]);
    }
    E[j][ql] = v;
  }
  __syncthreads();

  const int rg4 = (tid >> 4) * 4;
  const int cg4 = (tid & 15) * 4;
  const int sr  = tid >> 2;
  const int sk  = (tid & 3) * 8;
  float ss0 = 0.f, ss1 = 0.f, ss2 = 0.f, ss3 = 0.f;

  for (int R = 0; R < 4; ++R){
    const int i0 = R*64;
    const int nct = 2*R + 2;
    {
      const int i = i0 + sr, j0s = sk;
      float v[8] = {};
      if (i < MMAX && j0s <= i){
        const float* wr = Wg + rowS(i) + j0s;
        if (j0s + 7 <= i){
          float4 a = *(const float4*)wr, b = *(const float4*)(wr+4);
          v[0]=a.x; v[1]=a.y; v[2]=a.z; v[3]=a.w; v[4]=b.x; v[5]=b.y; v[6]=b.z; v[7]=b.w;
        } else {
          #pragma unroll
          for (int u = 0; u < 8; ++u) if (j0s + u <= i) v[u] = wr[u];
        }
      }
      #pragma unroll
      for (int u = 0; u < 8; ++u) Wt[0][sk+u][sr] = v[u];
    }
    __syncthreads();

    float acc[4][4] = {};
    for (int ct = 0; ct < nct; ++ct){
      const int buf = ct & 1;
      if (ct + 1 < nct){
        const int i = i0 + sr, j0s = (ct+1)*32 + sk;
        float v[8] = {};
        if (i < MMAX && j0s <= i){
          const float* wr = Wg + rowS(i) + j0s;
          if (j0s + 7 <= i){
            float4 a = *(const float4*)wr, b = *(const float4*)(wr+4);
            v[0]=a.x; v[1]=a.y; v[2]=a.z; v[3]=a.w; v[4]=b.x; v[5]=b.y; v[6]=b.z; v[7]=b.w;
          } else {
            #pragma unroll
            for (int u = 0; u < 8; ++u) if (j0s + u <= i) v[u] = wr[u];
          }
        }
        #pragma unroll
        for (int u = 0; u < 8; ++u) Wt[buf^1][sk+u][sr] = v[u];
      }
      const int j0 = ct*32;
      #pragma unroll 4
      for (int k = 0; k < 32; ++k){
        const float4 w = *(const float4*)&Wt[buf][k][rg4];
        const float4 e = *(const float4*)&E[j0+k][cg4];
        acc[0][0] += w.x*e.x; acc[0][1] += w.x*e.y; acc[0][2] += w.x*e.z; acc[0][3] += w.x*e.w;
        acc[1][0] += w.y*e.x; acc[1][1] += w.y*e.y; acc[1][2] += w.y*e.z; acc[1][3] += w.y*e.w;
        acc[2][0] += w.z*e.x; acc[2][1] += w.z*e.y; acc[2][2] += w.z*e.z; acc[2][3] += w.z*e.w;
        acc[3][0] += w.w*e.x; acc[3][1] += w.w*e.y; acc[3][2] += w.w*e.z; acc[3][3] += w.w*e.w;
      }
      __syncthreads();
    }
    ss0 += acc[0][0]*acc[0][0] + acc[1][0]*acc[1][0] + acc[2][0]*acc[2][0] + acc[3][0]*acc[3][0];
    ss1 += acc[0][1]*acc[0][1] + acc[1][1]*acc[1][1] + acc[2][1]*acc[2][1] + acc[3][1]*acc[3][1];
    ss2 += acc[0][2]*acc[0][2] + acc[1][2]*acc[1][2] + acc[2][2]*acc[2][2] + acc[3][2]*acc[3][2];
    ss3 += acc[0][3]*acc[0][3] + acc[1][3]*acc[1][3] + acc[2][3]*acc[2][3] + acc[3][3]*acc[3][3];
  }

  float* Rb = &Wt[0][0][0];
  const int rg = tid >> 4;
  Rb[rg*64 + cg4 + 0] = ss0;
  Rb[rg*64 + cg4 + 1] = ss1;
  Rb[rg*64 + cg4 + 2] = ss2;
  Rb[rg*64 + cg4 + 3] = ss3;
  __syncthreads();
  if (tid < 64){
    float tt = 0.f;
    #pragma unroll
    for (int g = 0; g < 16; ++g) tt += Rb[g*64 + tid];
    float quad = mmv - 2.f*mqp[tid] + qnp[tid] - tt;
    ws[OFF_QUAD + ((size_t)p*NQ + q0 + tid)*C + c] = quad;
  }
}

// ---------------- logits: mean over p ----------------
__global__ void k_logits(const float* ws, float* out){
  int lin = blockIdx.x*256 + threadIdx.x;
  if (lin < QL){
    float s = 0.f;
    for (int p = 0; p < P; ++p) s += ws[OFF_QUAD + (size_t)p*NQ*C + lin];
    out[lin] = -s * (1.0f/P);
  }
}

extern "C" void kernel_launch(void* const* d_in, const int* in_sizes, int n_in,
                              void* d_out, int out_size, void* d_ws, size_t ws_size,
                              hipStream_t stream){
  const float* X   = (const float*)d_in[0];
  const int*   lab = (const int*)d_in[1];
  const float* Qf  = (const float*)d_in[2];
  float* out = (float*)d_out;
  float* ws  = (float*)d_ws;

  k_setup   <<<1, 64, 0, stream>>>(lab, ws);
  k_gram    <<<dim3(7,7,P),  dim3(16,16), 0, stream>>>(X, ws);
  k_pstats_a<<<dim3(25,P), 256, 0, stream>>>(ws);
  k_pstats_b<<<P, 256, 0, stream>>>(ws);
  k_means   <<<P*C, 256, 0, stream>>>(X, ws, out);
  k_sq      <<<dim3(7,16,P), dim3(16,16), 0, stream>>>(X, Qf, ws);
  k_qstats  <<<dim3(16,P), 256, 0, stream>>>(ws);
  k_qnorm   <<<(P*NQ)/4, 256, 0, stream>>>(Qf, ws);
  k_factor  <<<P*C, NTF, 0, stream>>>(ws);
  k_apply   <<<dim3(16,C,P), 256, 0, stream>>>(ws);
  k_logits  <<<QL/256, 256, 0, stream>>>(ws, out);
}

// Round 8
// 825.407 us; speedup vs baseline: 2.3131x; 1.0925x over previous
//
#include <hip/hip_runtime.h>

// Problem constants (fixed by the reference)
#define P 8
#define T 200
#define C 20
#define F 512
#define NQ 1024
#define MAXN 40                    // max samples per class we support (true ~10±4)
#define MMAX (T + MAXN)            // 240
#define PACK ((MMAX*(MMAX+1))/2)   // 28920 packed lower-tri floats
#define PACKA 29280                // row-padded-to-4 packed layout = rowS(MMAX)
#define QL (NQ*C)                  // 20480 logits
#define NB 16                      // Cholesky panel width
#define NTF 512                    // k_factor block size (8 waves; 1024 forced VGPR<=64 -> spills, R7)

// Workspace layout (float offsets)
enum : int {
  OFF_G    = 0,                       // P*T*T      = 320000
  OFF_SQ   = OFF_G   + P*T*T,         // P*T*NQ     = 1638400
  OFF_G1   = OFF_SQ  + P*T*NQ,        // P*T
  OFF_GG   = OFF_G1  + P*T,           // P
  OFF_GM   = OFF_GG  + P,             // P*T*C
  OFF_GMC  = OFF_GM  + P*T*C,         // P*C
  OFF_MM   = OFF_GMC + P*C,           // P*C
  OFF_GQ   = OFF_MM  + P*C,           // P*NQ
  OFF_QN   = OFF_GQ  + P*NQ,          // P*NQ
  OFF_MQ   = OFF_QN  + P*NQ,          // P*C*NQ
  OFF_W    = OFF_MQ  + P*C*NQ,        // P*C*PACKA : packed FULL INVERSE W=L^-1, rows>=m zeroed
  OFF_QUAD = OFF_W   + P*C*PACKA,     // P*NQ*C
  OFF_CLSF = OFF_QUAD+ P*NQ*C,        // C*8 scalars
  OFF_INT  = OFF_CLSF+ C*8            // int region: counts[C], idx[C*MAXN]
};

__device__ __forceinline__ int offr(int i){ return (i*(i+1))>>1; }

// 4-aligned row-padded packed layout: row i at rowS(i), length padded to mult of 4.
__device__ __forceinline__ int rowS(int i){
  int a = i >> 2, r = i & 3;
  return 8*a*(a+1) + 4*r*(a+1);
}

// flat packed index e -> row i (offr layout, used for tile triangles)
__device__ __forceinline__ int row_of(int e){
  int i = (int)((sqrtf(8.f*(float)e + 1.f) - 1.f) * 0.5f);
  while (offr(i+1) <= e) ++i;
  while (offr(i) > e) --i;
  return i;
}

// flat index e -> row i in rowS layout
__device__ __forceinline__ int row_ofS(int e){
  int i = (int)sqrtf(2.f*(float)e);
  if (i > MMAX-1) i = MMAX-1;
  while (i < MMAX-1 && rowS(i+1) <= e) ++i;
  while (i > 0 && rowS(i) > e) --i;
  return i;
}

// ---------------- setup: counts, per-class index lists, scalars ----------------
__global__ void k_setup(const int* lab, float* ws){
  int c = threadIdx.x;
  if (c >= C) return;
  int* wsI = (int*)(ws + OFF_INT);
  int n = 0;
  for (int t = 0; t < T; ++t){
    if (lab[t] == c){ if (n < MAXN) wsI[C + c*MAXN + n] = t; ++n; }
  }
  if (n > MAXN) n = MAXN;
  wsI[c] = n;
  float nf    = (float)n;
  float nsafe = fmaxf(nf, 1.0f);
  float dn    = fmaxf(nf - 1.0f, 1.0f);
  float lam   = nsafe / (nsafe + 1.0f);
  float sv    = (1.0f - lam) / (float)(T - 1);
  float av    = lam / dn;
  float* cf = ws + OFF_CLSF + c*8;
  cf[0] = nsafe; cf[1] = dn; cf[2] = lam; cf[3] = sv; cf[4] = av;
  cf[5] = sqrtf(sv); cf[6] = sqrtf(av); cf[7] = 0.0f;
}

// ---------------- G = X X^T per p (200x200) ----------------
__global__ __launch_bounds__(256) void k_gram(const float* X, float* ws){
  __shared__ float Xi[32][33];
  __shared__ float Xj[32][33];
  const int p = blockIdx.z, i0 = blockIdx.y*32, j0 = blockIdx.x*32;
  const int tx = threadIdx.x, ty = threadIdx.y;
  const int tid = ty*16 + tx;
  const float* Xp = X + (size_t)p*T*F;
  float acc[2][2] = {{0.f,0.f},{0.f,0.f}};
  for (int kb = 0; kb < F; kb += 32){
    for (int e = tid; e < 32*32; e += 256){
      int r = e >> 5, kk = e & 31;
      Xi[r][kk] = (i0+r < T) ? Xp[(i0+r)*F + kb+kk] : 0.f;
      Xj[r][kk] = (j0+r < T) ? Xp[(j0+r)*F + kb+kk] : 0.f;
    }
    __syncthreads();
    for (int kk = 0; kk < 32; ++kk){
      float a0 = Xi[2*ty][kk],   a1 = Xi[2*ty+1][kk];
      float b0 = Xj[2*tx][kk],   b1 = Xj[2*tx+1][kk];
      acc[0][0] += a0*b0; acc[0][1] += a0*b1;
      acc[1][0] += a1*b0; acc[1][1] += a1*b1;
    }
    __syncthreads();
  }
  float* Gp = ws + OFF_G + (size_t)p*T*T;
  for (int a = 0; a < 2; ++a)
    for (int b = 0; b < 2; ++b){
      int i = i0 + 2*ty + a, j = j0 + 2*tx + b;
      if (i < T && j < T) Gp[i*T + j] = acc[a][b];
    }
}

// ---------------- per-p stats part A: g1 rows + Gm (coalesced, 200 blocks) ----------------
__global__ __launch_bounds__(256) void k_pstats_a(float* ws){
  const int p = blockIdx.y, bx = blockIdx.x;      // bx in [0,25)
  const int w = threadIdx.x >> 6, lane = threadIdx.x & 63;
  const int* wsI = (const int*)(ws + OFF_INT);
  const float* Gp = ws + OFF_G + (size_t)p*T*T;
  float* g1 = ws + OFF_G1 + p*T;
  float* Gm = ws + OFF_GM + (size_t)p*T*C;
  for (int rr = 0; rr < 2; ++rr){
    const int t = bx*8 + w*2 + rr;                // 25*8 = 200 rows exactly
    float s = 0.f;
    for (int u = lane; u < T; u += 64) s += Gp[t*T + u];
    for (int off = 32; off; off >>= 1) s += __shfl_down(s, off, 64);
    if (lane == 0) g1[t] = s * (1.0f/T);
    if (lane < C){
      int c = lane, nn = wsI[c];
      const int* idxc = wsI + C + c*MAXN;
      float sc = 0.f;
      for (int j = 0; j < nn; ++j) sc += Gp[t*T + idxc[j]];
      Gm[t*C + c] = sc / ws[OFF_CLSF + c*8];
    }
  }
}

// ---------------- per-p stats part B: gg, gmc, mm ----------------
__global__ __launch_bounds__(256) void k_pstats_b(float* ws){
  __shared__ float red[64];
  const int p = blockIdx.x, tid = threadIdx.x;
  const int* wsI = (const int*)(ws + OFF_INT);
  const float* g1 = ws + OFF_G1 + p*T;
  const float* Gm = ws + OFF_GM + (size_t)p*T*C;
  if (tid < 64){
    float s = 0.f;
    for (int t = tid; t < T; t += 64) s += g1[t];
    red[tid] = s;
  }
  __syncthreads();
  if (tid == 0){
    float s = 0.f;
    for (int k = 0; k < 64; ++k) s += red[k];
    ws[OFF_GG + p] = s * (1.0f/T);
  }
  if (tid < C){
    int c = tid, nn = wsI[c];
    const int* idxc = wsI + C + c*MAXN;
    float s = 0.f;
    for (int t = 0; t < T; ++t) s += Gm[t*C + c];
    ws[OFF_GMC + p*C + c] = s * (1.0f/T);
    float s2 = 0.f;
    for (int j = 0; j < nn; ++j) s2 += Gm[idxc[j]*C + c];
    ws[OFF_MM + p*C + c] = s2 / ws[OFF_CLSF + c*8];
  }
}

// ---------------- class means -> output part 2 ----------------
__global__ __launch_bounds__(256) void k_means(const float* X, const float* ws, float* out){
  const int blk = blockIdx.x, p = blk / C, c = blk % C;
  const int* wsI = (const int*)(ws + OFF_INT);
  const int n = wsI[c];
  const int* idxc = wsI + C + c*MAXN;
  const float nf = ws[OFF_CLSF + c*8];
  const float* Xp = X + (size_t)p*T*F;
  float* o = out + QL + (size_t)(p*C + c)*F;
  for (int f = threadIdx.x; f < F; f += 256){
    float s = 0.f;
    for (int j = 0; j < n; ++j) s += Xp[idxc[j]*F + f];
    o[f] = s / nf;
  }
}

// ---------------- SQ = X Q^T per p (200x1024) ----------------
__global__ __launch_bounds__(256) void k_sq(const float* X, const float* Qf, float* ws){
  __shared__ float Xt[32][33];
  __shared__ float Qt[64][33];
  const int p = blockIdx.z, t0 = blockIdx.x*32, q0 = blockIdx.y*64;
  const int tx = threadIdx.x, ty = threadIdx.y;
  const int tid = ty*16 + tx;
  const float* Xp = X  + (size_t)p*T*F;
  const float* Qp = Qf + (size_t)p*NQ*F;
  float acc[2][4] = {};
  for (int kb = 0; kb < F; kb += 32){
    for (int e = tid; e < 32*32; e += 256){
      int r = e >> 5, kk = e & 31;
      Xt[r][kk] = (t0+r < T) ? Xp[(t0+r)*F + kb+kk] : 0.f;
    }
    for (int e = tid; e < 64*32; e += 256){
      int r = e >> 5, kk = e & 31;
      Qt[r][kk] = Qp[(q0+r)*F + kb+kk];
    }
    __syncthreads();
    for (int kk = 0; kk < 32; ++kk){
      float a0 = Xt[2*ty][kk], a1 = Xt[2*ty+1][kk];
      float b0 = Qt[4*tx][kk], b1 = Qt[4*tx+1][kk], b2 = Qt[4*tx+2][kk], b3 = Qt[4*tx+3][kk];
      acc[0][0] += a0*b0; acc[0][1] += a0*b1; acc[0][2] += a0*b2; acc[0][3] += a0*b3;
      acc[1][0] += a1*b0; acc[1][1] += a1*b1; acc[1][2] += a1*b2; acc[1][3] += a1*b3;
    }
    __syncthreads();
  }
  float* SQp = ws + OFF_SQ + (size_t)p*T*NQ;
  for (int a = 0; a < 2; ++a){
    int t = t0 + 2*ty + a;
    if (t < T)
      for (int b = 0; b < 4; ++b)
        SQp[t*NQ + q0 + 4*tx + b] = acc[a][b];
  }
}

// ---------------- per-q stats: gq, mq (chunked, 128 blocks) ----------------
__global__ __launch_bounds__(256) void k_qstats(float* ws){
  __shared__ float red[4][64];
  const int p = blockIdx.y;
  const int qb = blockIdx.x*64;                   // gridDim.x = 16
  const int chunk = threadIdx.x >> 6, lane = threadIdx.x & 63;
  const int q = qb + lane;
  const int* wsI = (const int*)(ws + OFF_INT);
  const float* SQp = ws + OFF_SQ + (size_t)p*T*NQ;
  float s = 0.f;
  for (int t = chunk*50; t < chunk*50 + 50; ++t) s += SQp[t*NQ + q];
  red[chunk][lane] = s;
  __syncthreads();
  if (chunk == 0){
    float tot = red[0][lane] + red[1][lane] + red[2][lane] + red[3][lane];
    ws[OFF_GQ + p*NQ + q] = tot * (1.0f/T);
  }
  for (int c = chunk; c < C; c += 4){
    int nn = wsI[c];
    const int* idxc = wsI + C + c*MAXN;
    float sc = 0.f;
    for (int j = 0; j < nn; ++j) sc += SQp[idxc[j]*NQ + q];
    ws[OFF_MQ + ((size_t)(p*C + c))*NQ + q] = sc / ws[OFF_CLSF + c*8];
  }
}

// ---------------- qn = ||q||^2, one wave per row ----------------
__global__ __launch_bounds__(256) void k_qnorm(const float* Qf, float* ws){
  const int row  = blockIdx.x*4 + (threadIdx.x >> 6);
  const int lane = threadIdx.x & 63;
  const float4* q4p = (const float4*)(Qf + (size_t)row*F);
  float4 v0 = q4p[lane];
  float4 v1 = q4p[lane + 64];
  float s = v0.x*v0.x + v0.y*v0.y + v0.z*v0.z + v0.w*v0.w
          + v1.x*v1.x + v1.y*v1.y + v1.z*v1.z + v1.w*v1.w;
  for (int off = 32; off; off >>= 1) s += __shfl_down(s, off, 64);
  if (lane == 0) ws[OFF_QN + row] = s;
}

// ---------------- build M; blocked Cholesky (wave-shuffle diag); full blocked
//                  triangular inversion. rowS LDS layout, all-b128 hot loops.
//                  NTF=512: 2 waves/SIMD -> 256 VGPR budget, NO SPILLS (R7 lesson). ----------------
__global__ __launch_bounds__(NTF) void k_factor(float* ws){
  __shared__ float Lp[PACKA];           // 117120 B, rowS-packed lower triangle
  __shared__ float Sb[16*228];          // 14592 B inversion stage buffer
  __shared__ float Dv[NB][NB+1];        // 1088 B Dinv of current diag block
  const int blk = blockIdx.x, p = blk / C, c = blk % C;
  const int tid = threadIdx.x;
  const int* wsI = (const int*)(ws + OFF_INT);
  const int n = wsI[c];
  const int m = T + n;
  const int* idxc = wsI + C + c*MAXN;
  const float* cf = ws + OFF_CLSF + c*8;
  const float sv = cf[3], av = cf[4], sqsa = cf[5]*cf[6];
  const float* Gp  = ws + OFF_G  + (size_t)p*T*T;
  const float* g1p = ws + OFF_G1 + p*T;
  const float  ggv = ws[OFF_GG + p];
  const float* Gmp = ws + OFF_GM + (size_t)p*T*C;
  const float gmcv = ws[OFF_GMC + p*C + c];
  const float mmv  = ws[OFF_MM  + p*C + c];

  // ---- build M in rowS layout; pads and rows >= m zeroed ----
  for (int e = tid; e < PACKA; e += NTF){
    int i = row_ofS(e);
    int j = e - rowS(i);
    float v = 0.f;
    if (i < m && j <= i){
      if (i < T){
        v = sv*(Gp[i*T + j] - g1p[i] - g1p[j] + ggv);
        if (j == i) v += 1.0f;
      } else {
        int ua = idxc[i - T];
        if (j < T){
          v = sqsa*(Gp[ua*T + j] - Gmp[j*C + c] - g1p[ua] + gmcv);
        } else {
          int ub = idxc[j - T];
          v = av*(Gp[ua*T + ub] - Gmp[ua*C + c] - Gmp[ub*C + c] + mmv);
          if (j == i) v += 1.0f;
        }
      }
    }
    Lp[e] = v;
  }
  __syncthreads();

  // ---- blocked right-looking Cholesky ----
  for (int k0 = 0; k0 < m; k0 += NB){
    // (a) diag 16x16 Cholesky + inverse inside wave 0 (no barriers)
    if (tid < 64){
      const int lane = tid;
      float a[NB];
      #pragma unroll
      for (int j = 0; j < NB; ++j){
        a[j] = 0.f;
        if (lane < NB && j <= lane) a[j] = Lp[rowS(k0+lane) + k0 + j];
      }
      #pragma unroll
      for (int k = 0; k < NB; ++k){
        float akk = __shfl(a[k], k, 64);
        float inv = rsqrtf(akk);
        a[k] *= inv;
        #pragma unroll
        for (int j = k+1; j < NB; ++j){
          float ljk = __shfl(a[k], j, 64);
          a[j] -= a[k] * ljk;
        }
      }
      float x[NB];
      #pragma unroll
      for (int i = 0; i < NB; ++i){
        float Lii = __shfl(a[i], i, 64);
        float sxx = 0.f;
        #pragma unroll
        for (int k2 = 0; k2 < i; ++k2){
          float Lik = __shfl(a[k2], i, 64);
          sxx += Lik * x[k2];
        }
        float tt = ((i == lane) ? 1.f : 0.f) - sxx;
        x[i] = tt / Lii;
      }
      if (lane < NB){
        #pragma unroll
        for (int i = 0; i < NB; ++i){
          Dv[i][lane] = (i >= lane) ? x[i] : 0.f;
          if (i >= lane) Lp[rowS(k0+i) + k0 + lane] = x[i];
        }
      }
    }
    __syncthreads();

    // (b) panel update: L[r][k0+j] = sum_{kk<=j} A[r][k0+kk] * Dinv[j][kk]
    for (int r = k0 + NB + tid; r < m; r += NTF){
      const int o = rowS(r) + k0;
      float4 A0 = *(const float4*)&Lp[o];
      float4 A1 = *(const float4*)&Lp[o+4];
      float4 A2 = *(const float4*)&Lp[o+8];
      float4 A3 = *(const float4*)&Lp[o+12];
      float ar[NB] = {A0.x,A0.y,A0.z,A0.w, A1.x,A1.y,A1.z,A1.w,
                      A2.x,A2.y,A2.z,A2.w, A3.x,A3.y,A3.z,A3.w};
      float sr[NB];
      #pragma unroll
      for (int j = 0; j < NB; ++j){
        float s = 0.f;
        #pragma unroll
        for (int kk = 0; kk <= j; ++kk) s += ar[kk] * Dv[j][kk];
        sr[j] = s;
      }
      *(float4*)&Lp[o]    = make_float4(sr[0], sr[1], sr[2], sr[3]);
      *(float4*)&Lp[o+4]  = make_float4(sr[4], sr[5], sr[6], sr[7]);
      *(float4*)&Lp[o+8]  = make_float4(sr[8], sr[9], sr[10], sr[11]);
      *(float4*)&Lp[o+12] = make_float4(sr[12], sr[13], sr[14], sr[15]);
    }
    __syncthreads();

    // (c) trailing SYRK directly from Lp (b128 reads; rows >= m are zero)
    const int rs = m - k0 - NB;
    if (rs > 0){
      const int base = k0 + NB;
      const int nt4 = (rs + 3) >> 2;
      const int ntile = (nt4*(nt4+1)) >> 1;
      for (int e2 = tid; e2 < ntile; e2 += NTF){
        const int ti = row_of(e2);
        const int tj = e2 - offr(ti);
        const int gi0 = base + 4*ti, gj0 = base + 4*tj;
        const float* pa0 = &Lp[rowS(gi0)   + k0];
        const float* pa1 = &Lp[rowS(gi0+1) + k0];
        const float* pa2 = &Lp[rowS(gi0+2) + k0];
        const float* pa3 = &Lp[rowS(gi0+3) + k0];
        const float* pb0 = &Lp[rowS(gj0)   + k0];
        const float* pb1 = &Lp[rowS(gj0+1) + k0];
        const float* pb2 = &Lp[rowS(gj0+2) + k0];
        const float* pb3 = &Lp[rowS(gj0+3) + k0];
        float acc[4][4] = {};
        #pragma unroll
        for (int kk = 0; kk < NB; kk += 4){
          float4 a0 = *(const float4*)(pa0+kk);
          float4 a1 = *(const float4*)(pa1+kk);
          float4 a2 = *(const float4*)(pa2+kk);
          float4 a3 = *(const float4*)(pa3+kk);
          float4 b0 = *(const float4*)(pb0+kk);
          float4 b1 = *(const float4*)(pb1+kk);
          float4 b2 = *(const float4*)(pb2+kk);
          float4 b3 = *(const float4*)(pb3+kk);
          acc[0][0] += a0.x*b0.x + a0.y*b0.y + a0.z*b0.z + a0.w*b0.w;
          acc[0][1] += a0.x*b1.x + a0.y*b1.y + a0.z*b1.z + a0.w*b1.w;
          acc[0][2] += a0.x*b2.x + a0.y*b2.y + a0.z*b2.z + a0.w*b2.w;
          acc[0][3] += a0.x*b3.x + a0.y*b3.y + a0.z*b3.z + a0.w*b3.w;
          acc[1][0] += a1.x*b0.x + a1.y*b0.y + a1.z*b0.z + a1.w*b0.w;
          acc[1][1] += a1.x*b1.x + a1.y*b1.y + a1.z*b1.z + a1.w*b1.w;
          acc[1][2] += a1.x*b2.x + a1.y*b2.y + a1.z*b2.z + a1.w*b2.w;
          acc[1][3] += a1.x*b3.x + a1.y*b3.y + a1.z*b3.z + a1.w*b3.w;
          acc[2][0] += a2.x*b0.x + a2.y*b0.y + a2.z*b0.z + a2.w*b0.w;
          acc[2][1] += a2.x*b1.x + a2.y*b1.y + a2.z*b1.z + a2.w*b1.w;
          acc[2][2] += a2.x*b2.x + a2.y*b2.y + a2.z*b2.z + a2.w*b2.w;
          acc[2][3] += a2.x*b3.x + a2.y*b3.y + a2.z*b3.z + a2.w*b3.w;
          acc[3][0] += a3.x*b0.x + a3.y*b0.y + a3.z*b0.z + a3.w*b0.w;
          acc[3][1] += a3.x*b1.x + a3.y*b1.y + a3.z*b1.z + a3.w*b1.w;
          acc[3][2] += a3.x*b2.x + a3.y*b2.y + a3.z*b2.z + a3.w*b2.w;
          acc[3][3] += a3.x*b3.x + a3.y*b3.y + a3.z*b3.z + a3.w*b3.w;
        }
        #pragma unroll
        for (int u = 0; u < 4; ++u){
          const int gi = gi0 + u;
          if (gi < m){
            const int og = rowS(gi);
            if (gj0 + 3 <= gi){
              float4 t = *(float4*)&Lp[og + gj0];
              t.x -= acc[u][0]; t.y -= acc[u][1]; t.z -= acc[u][2]; t.w -= acc[u][3];
              *(float4*)&Lp[og + gj0] = t;
            } else {
              #pragma unroll
              for (int v = 0; v < 4; ++v){
                const int gj = gj0 + v;
                if (gj <= gi) Lp[og + gj] -= acc[u][v];
              }
            }
          }
        }
      }
    }
    __syncthreads();
  }

  // ---- full triangular inversion in place (ascending block-rows, all b128) ----
  for (int I = 1; I < MMAX/NB; ++I){
    const int i0 = I*NB;
    const int nct = i0 >> 2;
    const int rt = tid & 3, ct = tid >> 2;
    const int rt4 = rt*4;
    const int j0 = ct*4;
    int o0 = 0, o1 = 0, o2 = 0, o3 = 0;
    if (tid < 4*nct){
      const int r0 = i0 + rt4;
      o0 = rowS(r0); o1 = rowS(r0+1); o2 = rowS(r0+2); o3 = rowS(r0+3);
      float acc[4][4] = {};
      for (int k = j0; k < i0; k += 4){
        float4 l0 = *(const float4*)&Lp[o0+k];
        float4 l1 = *(const float4*)&Lp[o1+k];
        float4 l2 = *(const float4*)&Lp[o2+k];
        float4 l3 = *(const float4*)&Lp[o3+k];
        float4 x0 = *(const float4*)&Lp[rowS(k)  +j0];
        float4 x1 = *(const float4*)&Lp[rowS(k+1)+j0];
        float4 x2 = *(const float4*)&Lp[rowS(k+2)+j0];
        float4 x3 = *(const float4*)&Lp[rowS(k+3)+j0];
        acc[0][0] += l0.x*x0.x + l0.y*x1.x + l0.z*x2.x + l0.w*x3.x;
        acc[0][1] += l0.x*x0.y + l0.y*x1.y + l0.z*x2.y + l0.w*x3.y;
        acc[0][2] += l0.x*x0.z + l0.y*x1.z + l0.z*x2.z + l0.w*x3.z;
        acc[0][3] += l0.x*x0.w + l0.y*x1.w + l0.z*x2.w + l0.w*x3.w;
        acc[1][0] += l1.x*x0.x + l1.y*x1.x + l1.z*x2.x + l1.w*x3.x;
        acc[1][1] += l1.x*x0.y + l1.y*x1.y + l1.z*x2.y + l1.w*x3.y;
        acc[1][2] += l1.x*x0.z + l1.y*x1.z + l1.z*x2.z + l1.w*x3.z;
        acc[1][3] += l1.x*x0.w + l1.y*x1.w + l1.z*x2.w + l1.w*x3.w;
        acc[2][0] += l2.x*x0.x + l2.y*x1.x + l2.z*x2.x + l2.w*x3.x;
        acc[2][1] += l2.x*x0.y + l2.y*x1.y + l2.z*x2.y + l2.w*x3.y;
        acc[2][2] += l2.x*x0.z + l2.y*x1.z + l2.z*x2.z + l2.w*x3.z;
        acc[2][3] += l2.x*x0.w + l2.y*x1.w + l2.z*x2.w + l2.w*x3.w;
        acc[3][0] += l3.x*x0.x + l3.y*x1.x + l3.z*x2.x + l3.w*x3.x;
        acc[3][1] += l3.x*x0.y + l3.y*x1.y + l3.z*x2.y + l3.w*x3.y;
        acc[3][2] += l3.x*x0.z + l3.y*x1.z + l3.z*x2.z + l3.w*x3.z;
        acc[3][3] += l3.x*x0.w + l3.y*x1.w + l3.z*x2.w + l3.w*x3.w;
      }
      *(float4*)&Sb[(rt4  )*228 + j0] = make_float4(acc[0][0], acc[0][1], acc[0][2], acc[0][3]);
      *(float4*)&Sb[(rt4+1)*228 + j0] = make_float4(acc[1][0], acc[1][1], acc[1][2], acc[1][3]);
      *(float4*)&Sb[(rt4+2)*228 + j0] = make_float4(acc[2][0], acc[2][1], acc[2][2], acc[2][3]);
      *(float4*)&Sb[(rt4+3)*228 + j0] = make_float4(acc[3][0], acc[3][1], acc[3][2], acc[3][3]);
    }
    __syncthreads();
    if (tid < 4*nct){
      float acc[4][4] = {};
      for (int s = 0; s < rt4 + 4; ++s){
        const float d0 = Lp[o0 + i0 + s];   // pads beyond row give zero
        const float d1 = Lp[o1 + i0 + s];
        const float d2 = Lp[o2 + i0 + s];
        const float d3 = Lp[o3 + i0 + s];
        const float4 sv4 = *(const float4*)&Sb[s*228 + j0];
        acc[0][0] += d0*sv4.x; acc[0][1] += d0*sv4.y; acc[0][2] += d0*sv4.z; acc[0][3] += d0*sv4.w;
        acc[1][0] += d1*sv4.x; acc[1][1] += d1*sv4.y; acc[1][2] += d1*sv4.z; acc[1][3] += d1*sv4.w;
        acc[2][0] += d2*sv4.x; acc[2][1] += d2*sv4.y; acc[2][2] += d2*sv4.z; acc[2][3] += d2*sv4.w;
        acc[3][0] += d3*sv4.x; acc[3][1] += d3*sv4.y; acc[3][2] += d3*sv4.z; acc[3][3] += d3*sv4.w;
      }
      *(float4*)&Lp[o0 + j0] = make_float4(-acc[0][0], -acc[0][1], -acc[0][2], -acc[0][3]);
      *(float4*)&Lp[o1 + j0] = make_float4(-acc[1][0], -acc[1][1], -acc[1][2], -acc[1][3]);
      *(float4*)&Lp[o2 + j0] = make_float4(-acc[2][0], -acc[2][1], -acc[2][2], -acc[2][3]);
      *(float4*)&Lp[o3 + j0] = make_float4(-acc[3][0], -acc[3][1], -acc[3][2], -acc[3][3]);
    }
    __syncthreads();
  }

  // ---- store W = L^-1 (straight float4 copy; rows >= m forced to zero) ----
  float4* Wg4 = (float4*)(ws + OFF_W + (size_t)blk * PACKA);
  const float4* Lp4 = (const float4*)Lp;
  const int z4 = rowS(m) >> 2;
  for (int e4 = tid; e4 < PACKA/4; e4 += NTF){
    float4 v = Lp4[e4];
    if (e4 >= z4) v = make_float4(0.f, 0.f, 0.f, 0.f);
    Wg4[e4] = v;
  }
}

// ---------------- apply: z = W*e as tiled lower-tri GEMM; quad = ||d||^2 - ||z||^2 ----------------
__global__ __launch_bounds__(256) void k_apply(float* ws){
  __shared__ float E[256][64];        // e (zero-padded to 256 rows); 64 KB
  __shared__ float Wt[2][32][64];     // W tile, [k][r] col-major; 16 KB
  const int p = blockIdx.z, c = blockIdx.y, q0 = blockIdx.x*64;
  const int tid = threadIdx.x;
  const int* wsI = (const int*)(ws + OFF_INT);
  const int n = wsI[c], m = T + n;
  const int* idxc = wsI + C + c*MAXN;
  const float* cf = ws + OFF_CLSF + c*8;
  const float sqs = cf[5], sqa = cf[6];
  const float gmcv = ws[OFF_GMC + p*C + c];
  const float mmv  = ws[OFF_MM  + p*C + c];
  const float* Gmp = ws + OFF_GM + (size_t)p*T*C;
  const float* SQp = ws + OFF_SQ + (size_t)p*T*NQ;
  const float* gqp = ws + OFF_GQ + p*NQ + q0;
  const float* qnp = ws + OFF_QN + p*NQ + q0;
  const float* mqp = ws + OFF_MQ + ((size_t)(p*C + c))*NQ + q0;
  const float* Wg  = ws + OFF_W + (size_t)(p*C + c)*PACKA;

  for (int lin = tid; lin < 256*64; lin += 256){
    int j = lin >> 6, ql = lin & 63;
    float v = 0.f;
    if (j < T){
      v = sqs*(Gmp[j*C + c] - SQp[j*NQ + q0 + ql] - gmcv + gqp[ql]);
    } else if (j < m){
      int u = idxc[j - T];
      v = sqa*(Gmp[u*C + c] - SQp[u*NQ + q0 + ql] - mmv + mqp[ql]);
    }
    E[j][ql] = v;
  }
  __syncthreads();

  const int rg4 = (tid >> 4) * 4;
  const int cg4 = (tid & 15) * 4;
  const int sr  = tid >> 2;
  const int sk  = (tid & 3) * 8;
  float ss0 = 0.f, ss1 = 0.f, ss2 = 0.f, ss3 = 0.f;

  for (int R = 0; R < 4; ++R){
    const int i0 = R*64;
    const int nct = 2*R + 2;
    {
      const int i = i0 + sr, j0s = sk;
      float v[8] = {};
      if (i < MMAX && j0s <= i){
        const float* wr = Wg + rowS(i) + j0s;
        if (j0s + 7 <= i){
          float4 a = *(const float4*)wr, b = *(const float4*)(wr+4);
          v[0]=a.x; v[1]=a.y; v[2]=a.z; v[3]=a.w; v[4]=b.x; v[5]=b.y; v[6]=b.z; v[7]=b.w;
        } else {
          #pragma unroll
          for (int u = 0; u < 8; ++u) if (j0s + u <= i) v[u] = wr[u];
        }
      }
      #pragma unroll
      for (int u = 0; u < 8; ++u) Wt[0][sk+u][sr] = v[u];
    }
    __syncthreads();

    float acc[4][4] = {};
    for (int ct = 0; ct < nct; ++ct){
      const int buf = ct & 1;
      if (ct + 1 < nct){
        const int i = i0 + sr, j0s = (ct+1)*32 + sk;
        float v[8] = {};
        if (i < MMAX && j0s <= i){
          const float* wr = Wg + rowS(i) + j0s;
          if (j0s + 7 <= i){
            float4 a = *(const float4*)wr, b = *(const float4*)(wr+4);
            v[0]=a.x; v[1]=a.y; v[2]=a.z; v[3]=a.w; v[4]=b.x; v[5]=b.y; v[6]=b.z; v[7]=b.w;
          } else {
            #pragma unroll
            for (int u = 0; u < 8; ++u) if (j0s + u <= i) v[u] = wr[u];
          }
        }
        #pragma unroll
        for (int u = 0; u < 8; ++u) Wt[buf^1][sk+u][sr] = v[u];
      }
      const int j0 = ct*32;
      #pragma unroll 4
      for (int k = 0; k < 32; ++k){
        const float4 w = *(const float4*)&Wt[buf][k][rg4];
        const float4 e = *(const float4*)&E[j0+k][cg4];
        acc[0][0] += w.x*e.x; acc[0][1] += w.x*e.y; acc[0][2] += w.x*e.z; acc[0][3] += w.x*e.w;
        acc[1][0] += w.y*e.x; acc[1][1] += w.y*e.y; acc[1][2] += w.y*e.z; acc[1][3] += w.y*e.w;
        acc[2][0] += w.z*e.x; acc[2][1] += w.z*e.y; acc[2][2] += w.z*e.z; acc[2][3] += w.z*e.w;
        acc[3][0] += w.w*e.x; acc[3][1] += w.w*e.y; acc[3][2] += w.w*e.z; acc[3][3] += w.w*e.w;
      }
      __syncthreads();
    }
    ss0 += acc[0][0]*acc[0][0] + acc[1][0]*acc[1][0] + acc[2][0]*acc[2][0] + acc[3][0]*acc[3][0];
    ss1 += acc[0][1]*acc[0][1] + acc[1][1]*acc[1][1] + acc[2][1]*acc[2][1] + acc[3][1]*acc[3][1];
    ss2 += acc[0][2]*acc[0][2] + acc[1][2]*acc[1][2] + acc[2][2]*acc[2][2] + acc[3][2]*acc[3][2];
    ss3 += acc[0][3]*acc[0][3] + acc[1][3]*acc[1][3] + acc[2][3]*acc[2][3] + acc[3][3]*acc[3][3];
  }

  float* Rb = &Wt[0][0][0];
  const int rg = tid >> 4;
  Rb[rg*64 + cg4 + 0] = ss0;
  Rb[rg*64 + cg4 + 1] = ss1;
  Rb[rg*64 + cg4 + 2] = ss2;
  Rb[rg*64 + cg4 + 3] = ss3;
  __syncthreads();
  if (tid < 64){
    float tt = 0.f;
    #pragma unroll
    for (int g = 0; g < 16; ++g) tt += Rb[g*64 + tid];
    float quad = mmv - 2.f*mqp[tid] + qnp[tid] - tt;
    ws[OFF_QUAD + ((size_t)p*NQ + q0 + tid)*C + c] = quad;
  }
}

// ---------------- logits: mean over p ----------------
__global__ void k_logits(const float* ws, float* out){
  int lin = blockIdx.x*256 + threadIdx.x;
  if (lin < QL){
    float s = 0.f;
    for (int p = 0; p < P; ++p) s += ws[OFF_QUAD + (size_t)p*NQ*C + lin];
    out[lin] = -s * (1.0f/P);
  }
}

extern "C" void kernel_launch(void* const* d_in, const int* in_sizes, int n_in,
                              void* d_out, int out_size, void* d_ws, size_t ws_size,
                              hipStream_t stream){
  const float* X   = (const float*)d_in[0];
  const int*   lab = (const int*)d_in[1];
  const float* Qf  = (const float*)d_in[2];
  float* out = (float*)d_out;
  float* ws  = (float*)d_ws;

  k_setup   <<<1, 64, 0, stream>>>(lab, ws);
  k_gram    <<<dim3(7,7,P),  dim3(16,16), 0, stream>>>(X, ws);
  k_pstats_a<<<dim3(25,P), 256, 0, stream>>>(ws);
  k_pstats_b<<<P, 256, 0, stream>>>(ws);
  k_means   <<<P*C, 256, 0, stream>>>(X, ws, out);
  k_sq      <<<dim3(7,16,P), dim3(16,16), 0, stream>>>(X, Qf, ws);
  k_qstats  <<<dim3(16,P), 256, 0, stream>>>(ws);
  k_qnorm   <<<(P*NQ)/4, 256, 0, stream>>>(Qf, ws);
  k_factor  <<<P*C, NTF, 0, stream>>>(ws);
  k_apply   <<<dim3(16,C,P), 256, 0, stream>>>(ws);
  k_logits  <<<QL/256, 256, 0, stream>>>(ws, out);
}